// Round 5
// baseline (1955.155 us; speedup 1.0000x reference)
//
#include <hip/hip_runtime.h>
#include <stdint.h>

#define T_DIM 512
#define B_DIM 256
#define OBS_DIM 128
#define H_DIM 256
#define A_DIM 32
#define TB (T_DIM*B_DIM)   // 131072

typedef unsigned short u16;
typedef unsigned int   u32;
typedef _Float16 half2v __attribute__((ext_vector_type(2)));
typedef __attribute__((ext_vector_type(8))) short short8;   // 8 bf16 (4 VGPRs)
typedef __attribute__((ext_vector_type(4))) float f32x4;
typedef __attribute__((ext_vector_type(4))) u32   u32x4;

__device__ __forceinline__ float bf2f(u16 v){ return __uint_as_float(((u32)v)<<16); }
__device__ __forceinline__ u16 f2bf(float f){
    u32 x = __float_as_uint(f);
    u32 r = x + 0x7fffu + ((x>>16)&1u);   // round-to-nearest-even
    return (u16)(r>>16);
}
__device__ __forceinline__ float2 bfpair(u32 u){
    return make_float2(__uint_as_float(u<<16), __uint_as_float(u & 0xffff0000u));
}

// packed-f16-pair dot: acc += a.lo*b.lo + a.hi*b.hi
__device__ __forceinline__ float dot2(u32 a, u32 b, float c){
#if __has_builtin(__builtin_amdgcn_fdot2)
    return __builtin_amdgcn_fdot2(__builtin_bit_cast(half2v,a),
                                  __builtin_bit_cast(half2v,b), c, false);
#else
    half2v ha = __builtin_bit_cast(half2v,a), hb = __builtin_bit_cast(half2v,b);
    return fmaf((float)ha[0],(float)hb[0], fmaf((float)ha[1],(float)hb[1], c));
#endif
}

// ---------------------------------------------------------------------------
// dones dtype probe (u8 bool vs i32 vs f32) via nonzero byte positions mod 4.
// ---------------------------------------------------------------------------
__global__ void zero_flags_kernel(int* p){ if(threadIdx.x<4) p[threadIdx.x]=0; }

__global__ void detect_kernel(const unsigned char* __restrict__ d, int n, int* __restrict__ flags){
    int f=0;
    for(int p = blockIdx.x*blockDim.x+threadIdx.x; p<n; p += gridDim.x*blockDim.x){
        if(d[p]){ int m=p&3; if(m==1) f|=1; else if(m>=2) f|=2; }
    }
    if(f) atomicOr(flags, f);
}

// concat b_a1(256) | b_c1(256) -> b_ac(512) for the fused head-1 GEMM
__global__ void concat_bias_kernel(const float* __restrict__ a, const float* __restrict__ b,
                                   float* __restrict__ dst){
    int i = threadIdx.x;
    dst[i] = a[i];
    dst[256 + i] = b[i];
}

// ---------------------------------------------------------------------------
// Recurrent weights -> packed f16 pairs: dst[((m*32+q)*256 + j)*4 + e] packs
// k=2*(4q+e), 2*(4q+e)+1 of column j of matrix m (q covers k=8q..8q+7).
// ---------------------------------------------------------------------------
__global__ void cvt_wt_kernel(const float* __restrict__ Whr, const float* __restrict__ Whz,
                              const float* __restrict__ Whn, u32* __restrict__ dst){
    int i = blockIdx.x*blockDim.x + threadIdx.x;
    if(i >= 3*32*256*4) return;
    int e = i & 3;
    int j = (i >> 2) & 255;
    int q = (i >> 10) & 31;
    int m = i >> 15;
    const float* W = (m==0) ? Whr : (m==1) ? Whz : Whn;
    int kp = q*4 + e, k = 2*kp;
    _Float16 lo = (_Float16)W[(size_t)k    *H_DIM + j];
    _Float16 hi = (_Float16)W[(size_t)(k+1)*H_DIM + j];
    dst[i] = (u32)__builtin_bit_cast(u16,lo) | ((u32)__builtin_bit_cast(u16,hi) << 16);
}

// GEMM weight f32 [K][N] -> bf16 transposed [N][K]
__global__ void cvt_wT_kernel(const float* __restrict__ W, u16* __restrict__ dst,
                              int K, int N){
    int i = blockIdx.x*blockDim.x + threadIdx.x;
    if(i >= K*N) return;
    int n = i / K;
    int k = i - n*K;
    dst[i] = f2bf(W[(size_t)k*N + n]);
}

// ---------------------------------------------------------------------------
// MFMA bf16 GEMM: C[M,N](bf16) = opt_relu(A @ Bt^T + bias), Bt bf16 [N][K].
// A is bf16 (AF32=0) or f32 converted during staging (AF32=1).
// 128x128 tile, BK=32, 4 waves 2x2, 16x mfma_f32_16x16x32_bf16 each.
// ---------------------------------------------------------------------------
template<int RELU, int AF32>
__global__ __launch_bounds__(256, 2)
void gemm_mfma_kernel(const void* __restrict__ A_, const u16* __restrict__ Bt,
                      const float* __restrict__ bias, u16* __restrict__ C,
                      int M, int N, int K)
{
    __shared__ u16 As[128*32];
    __shared__ u16 Bs[128*32];
    const int tid  = threadIdx.x;
    const int wave = tid >> 6;
    const int lane = tid & 63;
    const int ln15 = lane & 15;
    const int quad = lane >> 4;
    const int wm = wave & 1, wn = wave >> 1;
    const int rowBase = blockIdx.y*128;
    const int colBase = blockIdx.x*128;

    f32x4 acc[4][4] = {};

    const int sr = tid >> 1;
    const int sc = (tid & 1) * 16;

    for(int kb = 0; kb < K; kb += 32){
        if(AF32){
            const float* af = (const float*)A_;
            const float* ag = af + (size_t)(rowBase+sr)*K + kb + sc;
            float4 f0 = *(const float4*)ag;
            float4 f1 = *(const float4*)(ag+4);
            float4 f2 = *(const float4*)(ag+8);
            float4 f3 = *(const float4*)(ag+12);
            u16 tmp[16] = { f2bf(f0.x),f2bf(f0.y),f2bf(f0.z),f2bf(f0.w),
                            f2bf(f1.x),f2bf(f1.y),f2bf(f1.z),f2bf(f1.w),
                            f2bf(f2.x),f2bf(f2.y),f2bf(f2.z),f2bf(f2.w),
                            f2bf(f3.x),f2bf(f3.y),f2bf(f3.z),f2bf(f3.w) };
            *(uint4*)&As[sr*32 + sc]     = *(const uint4*)&tmp[0];
            *(uint4*)&As[sr*32 + sc + 8] = *(const uint4*)&tmp[8];
        } else {
            const u16* ab = (const u16*)A_;
            const u16* ag = ab + (size_t)(rowBase+sr)*K + kb + sc;
            uint4 av0 = *(const uint4*)ag;
            uint4 av1 = *(const uint4*)(ag+8);
            *(uint4*)&As[sr*32 + sc]     = av0;
            *(uint4*)&As[sr*32 + sc + 8] = av1;
        }
        {
            const u16* bg = Bt + (size_t)(colBase+sr)*K + kb + sc;
            uint4 bv0 = *(const uint4*)bg;
            uint4 bv1 = *(const uint4*)(bg+8);
            *(uint4*)&Bs[sr*32 + sc]     = bv0;
            *(uint4*)&Bs[sr*32 + sc + 8] = bv1;
        }
        __syncthreads();

        short8 af[4], bf[4];
        #pragma unroll
        for(int mt=0;mt<4;mt++)
            af[mt] = *(const short8*)&As[(wm*64+mt*16+ln15)*32 + quad*8];
        #pragma unroll
        for(int nt=0;nt<4;nt++)
            bf[nt] = *(const short8*)&Bs[(wn*64+nt*16+ln15)*32 + quad*8];
        #pragma unroll
        for(int mt=0;mt<4;mt++){
            #pragma unroll
            for(int nt=0;nt<4;nt++){
                acc[mt][nt] = __builtin_amdgcn_mfma_f32_16x16x32_bf16(
                                  af[mt], bf[nt], acc[mt][nt], 0, 0, 0);
            }
        }
        __syncthreads();
    }

    #pragma unroll
    for(int nt=0;nt<4;nt++){
        int n = colBase + wn*64 + nt*16 + ln15;
        float bv = bias[n];
        #pragma unroll
        for(int mt=0;mt<4;mt++){
            #pragma unroll
            for(int r=0;r<4;r++){
                int m = rowBase + wm*64 + mt*16 + quad*4 + r;
                float v = acc[mt][nt][r] + bv;
                if(RELU) v = fmaxf(v, 0.f);
                C[(size_t)m*N + n] = f2bf(v);
            }
        }
    }
}

// ---------------------------------------------------------------------------
// GRU scan v5: 256 blocks (one batch row) x 256 threads (4 waves, 1/SIMD).
// R4 post-mortem: MFMA scan = latency chain (Mfma/VALU both 6%) -- reverted.
// R1-R3 lesson: any weight array above the allocator's occupancy-derived
// arch-VGPR target gets AGPR-parked, and VOP3P v_dot2 then pays a
// v_accvgpr_read per use. Fix: make the budget 512 by forcing 1 wave/SIMD
// (amdgpu_waves_per_eu(1,1)). Thread j owns the ENTIRE column j of all three
// matrices: 3x128 = 384 packed-f16 u32 + ~30 working set ~= 415 <= 512.
// Parking cannot help occupancy here (unified file, max already 1/SIMD).
// Structural bonus vs R2: no partial-sum exchange at all -- each thread
// computes full r/z/n dots for its column; one barrier per step (h dbuf).
// Latency at 1 wave/SIMD is covered by 6-way accumulator ILP in the dot loop.
// ---------------------------------------------------------------------------
__global__ __attribute__((amdgpu_flat_work_group_size(256,256), amdgpu_waves_per_eu(1,1)))
void scan_kernel(const u16* __restrict__ gi, const void* __restrict__ dones,
                 const int* __restrict__ flags, const u32x4* __restrict__ Wt4,
                 const float* __restrict__ bhn, float* __restrict__ h_carry,
                 u16* __restrict__ y, int t0, int Tc)
{
    __shared__ __align__(16) u32 hbuf[2][128];   // 256 packed f16 each
    const int j   = threadIdx.x;   // column 0..255
    const int row = blockIdx.x;
    const int fl  = flags[0];
    const int mode = (fl&1) ? 0 : ((fl&2) ? 2 : 1);  // 0=u8, 1=i32, 2=f32

    auto getdone = [&](int t)->bool{
        int idx = t*B_DIM + row;
        if(mode==0) return ((const unsigned char*)dones)[idx] != 0;
        if(mode==1) return ((const int*)dones)[idx] != 0;
        return ((const float*)dones)[idx] != 0.f;
    };

    // ---- one-time weight load: full k=256 of column j, all three mats ----
    const u32x4* baseR = Wt4 + (size_t)( 0)*256 + j;
    const u32x4* baseZ = Wt4 + (size_t)(32)*256 + j;
    const u32x4* baseN = Wt4 + (size_t)(64)*256 + j;
    u32 wr[128], wz[128], wn[128];
    #pragma unroll
    for(int q=0;q<32;q++){
        u32x4 tr = baseR[(size_t)q*256]; wr[4*q]=tr[0]; wr[4*q+1]=tr[1]; wr[4*q+2]=tr[2]; wr[4*q+3]=tr[3];
        u32x4 tz = baseZ[(size_t)q*256]; wz[4*q]=tz[0]; wz[4*q+1]=tz[1]; wz[4*q+2]=tz[2]; wz[4*q+3]=tz[3];
        u32x4 tn = baseN[(size_t)q*256]; wn[4*q]=tn[0]; wn[4*q+1]=tn[1]; wn[4*q+2]=tn[2]; wn[4*q+3]=tn[3];
    }
    #pragma unroll
    for(int q=0;q<128;q+=4){
        asm volatile("" : "+v"(wr[q  ]),"+v"(wr[q+1]),"+v"(wr[q+2]),"+v"(wr[q+3]),
                          "+v"(wz[q  ]),"+v"(wz[q+1]),"+v"(wz[q+2]),"+v"(wz[q+3]),
                          "+v"(wn[q  ]),"+v"(wn[q+1]),"+v"(wn[q+2]),"+v"(wn[q+3]));
    }

    const float bh = bhn[j];
    float hoj;
    {
        bool d0 = getdone(t0);
        hoj = d0 ? 0.f : h_carry[(size_t)row*H_DIM + j];
        ((_Float16*)hbuf[0])[j] = (_Float16)hoj;
    }
    __syncthreads();

    int cur = 0;
    for(int t=0; t<Tc; ++t){
        // gate-input loads up front (latency hides under the dot phase)
        size_t gbase = ((size_t)t*B_DIM + row)*768;
        float ir  = bf2f(gi[gbase + j]);
        float izv = bf2f(gi[gbase + 256 + j]);
        float inn = bf2f(gi[gbase + 512 + j]);
        bool  dn  = (t < Tc-1) ? getdone(t0+t+1) : false;

        // full-k dots for column j, all three matrices. hv is a wave-uniform
        // broadcast LDS read (conflict-free); 6 accumulators give the single
        // resident wave enough ILP to saturate the VALU pipe.
        float r0=0.f,r1=0.f,z0=0.f,z1=0.f,n0=0.f,n1=0.f;
        const u32x4* hb = (const u32x4*)hbuf[cur];
        #pragma unroll
        for(int q=0;q<32;q++){
            u32x4 hv = hb[q];
            r0 = dot2(wr[4*q  ], hv[0], r0); r1 = dot2(wr[4*q+1], hv[1], r1);
            r0 = dot2(wr[4*q+2], hv[2], r0); r1 = dot2(wr[4*q+3], hv[3], r1);
            z0 = dot2(wz[4*q  ], hv[0], z0); z1 = dot2(wz[4*q+1], hv[1], z1);
            z0 = dot2(wz[4*q+2], hv[2], z0); z1 = dot2(wz[4*q+3], hv[3], z1);
            n0 = dot2(wn[4*q  ], hv[0], n0); n1 = dot2(wn[4*q+1], hv[1], n1);
            n0 = dot2(wn[4*q+2], hv[2], n0); n1 = dot2(wn[4*q+3], hv[3], n1);
        }

        float r = 1.f/(1.f + __expf(-(ir  + r0 + r1)));
        float z = 1.f/(1.f + __expf(-(izv + z0 + z1)));
        float x = inn + r*(n0 + n1 + bh);
        float e2 = __expf(2.f*x);
        float n = 1.f - 2.f/(e2 + 1.f);          // tanh(x)
        float hn = (1.f - z)*n + z*hoj;
        y[((size_t)t*B_DIM + row)*H_DIM + j] = f2bf(hn);
        hoj = dn ? 0.f : hn;                     // dn=false on last chunk step
        ((_Float16*)hbuf[cur^1])[j] = (_Float16)hoj;
        __syncthreads();
        cur ^= 1;
    }

    h_carry[(size_t)row*H_DIM + j] = hoj;  // raw carry
}

// ---------------------------------------------------------------------------
// Actor head stage 2: logits[rows,32] = ah[rows,:256 of ld] @ W_a2 + b_a2 - (1-avail)*1e10
// ---------------------------------------------------------------------------
__global__ __launch_bounds__(256)
void actor2_kernel(const u16* __restrict__ ah, int ld, const float* __restrict__ W_a2,
                   const float* __restrict__ b_a2, const float* __restrict__ avail,
                   float* __restrict__ logits)
{
    __shared__ u16 ahs[64][264];
    const int tid = threadIdx.x;
    const int r0 = blockIdx.x*64;
    {
        int row = tid & 63;
        int c0 = (tid >> 6) * 64;
        const uint4* gp = (const uint4*)(ah + (size_t)(r0+row)*ld + c0);
        #pragma unroll
        for(int q=0;q<8;q++){
            uint4 u = gp[q];
            u32* dst = (u32*)&ahs[row][c0 + q*8];
            dst[0]=u.x; dst[1]=u.y; dst[2]=u.z; dst[3]=u.w;
        }
    }
    __syncthreads();
    const int c  = tid & 31;
    const int rg = tid >> 5;   // 0..7
    float acc[8]={0.f,0.f,0.f,0.f,0.f,0.f,0.f,0.f};
    float bc = b_a2[c];
    for(int k=0;k<H_DIM;k+=4){
        float w0 = W_a2[(k+0)*A_DIM + c];
        float w1 = W_a2[(k+1)*A_DIM + c];
        float w2 = W_a2[(k+2)*A_DIM + c];
        float w3 = W_a2[(k+3)*A_DIM + c];
        #pragma unroll
        for(int rr=0;rr<8;rr++){
            uint2 av = *(const uint2*)&ahs[rg*8+rr][k];
            float2 p0 = bfpair(av.x), p1 = bfpair(av.y);
            acc[rr] = fmaf(p0.x,w0,fmaf(p0.y,w1,fmaf(p1.x,w2,fmaf(p1.y,w3,acc[rr]))));
        }
    }
    #pragma unroll
    for(int rr=0;rr<8;rr++){
        int grow = r0 + rg*8 + rr;
        float av = avail[(size_t)grow*A_DIM + c];
        logits[(size_t)grow*A_DIM + c] = acc[rr] + bc - (1.f-av)*1e10f;
    }
}

// ---------------------------------------------------------------------------
// Critic head stage 2: value[row] = ch[row,:256 of ld] @ W_c2 + b_c2. Wave per row.
// ---------------------------------------------------------------------------
__global__ __launch_bounds__(256)
void critic2_kernel(const u16* __restrict__ ch, int ld, const float* __restrict__ W_c2,
                    const float* __restrict__ b_c2, float* __restrict__ value)
{
    const int lane = threadIdx.x & 63;
    const int wid  = threadIdx.x >> 6;
    const int row  = blockIdx.x*4 + wid;
    uint2 av = *(const uint2*)(ch + (size_t)row*ld + lane*4);
    float2 p0 = bfpair(av.x), p1 = bfpair(av.y);
    float4 wv = *(const float4*)(W_c2 + lane*4);
    float acc = p0.x*wv.x + p0.y*wv.y + p1.x*wv.z + p1.y*wv.w;
    #pragma unroll
    for(int off=32; off>0; off>>=1) acc += __shfl_down(acc, off, 64);
    if(lane==0) value[row] = acc + b_c2[0];
}

// ---------------------------------------------------------------------------
extern "C" void kernel_launch(void* const* d_in, const int* in_sizes, int n_in,
                              void* d_out, int out_size, void* d_ws, size_t ws_size,
                              hipStream_t stream)
{
    const float* hidden = (const float*)d_in[0];
    const float* obs    = (const float*)d_in[1];
    const void*  dones  = d_in[2];
    const float* avail  = (const float*)d_in[3];
    const float* W_emb  = (const float*)d_in[4];
    const float* b_emb  = (const float*)d_in[5];
    const float* Wi     = (const float*)d_in[6];
    const float* bi     = (const float*)d_in[7];
    const float* Whr    = (const float*)d_in[8];
    const float* Whz    = (const float*)d_in[9];
    const float* Whn    = (const float*)d_in[10];
    const float* bhn    = (const float*)d_in[11];
    const float* W_a1   = (const float*)d_in[12];
    const float* b_a1   = (const float*)d_in[13];
    const float* W_a2   = (const float*)d_in[14];
    const float* b_a2   = (const float*)d_in[15];
    const float* W_c1   = (const float*)d_in[16];
    const float* b_c1   = (const float*)d_in[17];
    const float* W_c2   = (const float*)d_in[18];
    const float* b_c2   = (const float*)d_in[19];

    float* out_hidden = (float*)d_out;                       // 65536
    float* out_logits = out_hidden + (size_t)B_DIM*H_DIM;    // 4194304
    float* out_value  = out_logits + (size_t)TB*A_DIM;       // 131072

    // ---- workspace layout (chunk size adapted to ws_size, deterministic) ----
    // fixed: wt_b + wiT + wacT(fused a1|c1) + wembT + h_carry + flags + b_ac
    const size_t fixed = 393216 + 393216 + 262144 + 65536 + 262144 + 256 + 2048;
    int Tc = 4;
    for(int cand = 64; cand >= 4; cand >>= 1){
        size_t need = fixed + (size_t)cand*(393216 /*gi*/ + 262144 /*emb|ac*/ + 131072 /*y*/);
        if(need <= ws_size){ Tc = cand; break; }
    }
    const int NC = T_DIM / Tc;

    uint8_t* ws = (uint8_t*)d_ws;
    size_t off = 0;
    u32*  wt_b    = (u32*)(ws + off); off += 393216;   // scan weights, packed f16
    u16*  wiT     = (u16*)(ws + off); off += 393216;   // Wi^T bf16 [768][256]
    u16*  wacT    = (u16*)(ws + off); off += 262144;   // [W_a1^T | W_c1^T] bf16 [512][256]
    u16*  wembT   = (u16*)(ws + off); off += 65536;    // W_emb^T bf16 [256][128]
    float* h_carry= (float*)(ws + off); off += 262144;
    int*  flags   = (int*)(ws + off); off += 256;
    float* b_ac   = (float*)(ws + off); off += 2048;   // b_a1|b_c1 (512 f32)
    u16*  gi_c    = (u16*)(ws + off); off += (size_t)Tc*393216;
    u16*  embac_c = (u16*)(ws + off); off += (size_t)Tc*262144;  // emb [Mc][256], later ac [Mc][512]
    u16*  y_c     = (u16*)(ws + off); off += (size_t)Tc*131072;
    u16*  emb_c   = embac_c;
    u16*  ac_c    = embac_c;

    zero_flags_kernel<<<1, 64, 0, stream>>>(flags);
    detect_kernel<<<64, 256, 0, stream>>>((const unsigned char*)dones, TB, flags);
    cvt_wt_kernel<<<384, 256, 0, stream>>>(Whr, Whz, Whn, wt_b);
    cvt_wT_kernel<<<768, 256, 0, stream>>>(Wi,   wiT,  256, 768);
    cvt_wT_kernel<<<256, 256, 0, stream>>>(W_a1, wacT,          256, 256);
    cvt_wT_kernel<<<256, 256, 0, stream>>>(W_c1, wacT + 65536,  256, 256);
    cvt_wT_kernel<<<128, 256, 0, stream>>>(W_emb, wembT, 128, 256);
    concat_bias_kernel<<<1, 256, 0, stream>>>(b_a1, b_c1, b_ac);
    hipMemcpyAsync(h_carry, hidden, (size_t)B_DIM*H_DIM*sizeof(float),
                   hipMemcpyDeviceToDevice, stream);

    const int Mc = Tc*B_DIM;
    const int gy = Mc/128;

    for(int c = 0; c < NC; ++c){
        const int t0 = c*Tc;
        const float* obs_c = obs + (size_t)t0*B_DIM*OBS_DIM;
        // emb = relu(obs @ W_emb + b_emb)  (MFMA, f32 A converted in staging)
        gemm_mfma_kernel<1,1><<<dim3(2,gy), 256, 0, stream>>>(obs_c, wembT, b_emb, emb_c, Mc, 256, 128);
        // gi = emb @ Wi + bi  (MFMA)
        gemm_mfma_kernel<0,0><<<dim3(6,gy), 256, 0, stream>>>(emb_c, wiT, bi, gi_c, Mc, 768, 256);
        // GRU scan chunk: 256 blocks (one per batch row) x 256 threads
        scan_kernel<<<256, 256, 0, stream>>>(gi_c, dones, flags, (const u32x4*)wt_b,
                                             bhn, h_carry, y_c, t0, Tc);
        // fused actor1|critic1 head: [Mc][512] = relu(y @ [W_a1|W_c1] + b_ac)
        gemm_mfma_kernel<1,0><<<dim3(4,gy), 256, 0, stream>>>(y_c, wacT, b_ac, ac_c, Mc, 512, 256);
        actor2_kernel<<<Mc/64, 256, 0, stream>>>(ac_c, 512, W_a2, b_a2,
                                                 avail + (size_t)t0*B_DIM*A_DIM,
                                                 out_logits + (size_t)t0*B_DIM*A_DIM);
        critic2_kernel<<<Mc/4, 256, 0, stream>>>(ac_c + 256, 512, W_c2, b_c2,
                                                 out_value + (size_t)t0*B_DIM);
    }

    hipMemcpyAsync(out_hidden, h_carry, (size_t)B_DIM*H_DIM*sizeof(float),
                   hipMemcpyDeviceToDevice, stream);
}

// Round 6
// 1634.713 us; speedup vs baseline: 1.1960x; 1.1960x over previous
//
#include <hip/hip_runtime.h>
#include <stdint.h>

#define T_DIM 512
#define B_DIM 256
#define OBS_DIM 128
#define H_DIM 256
#define A_DIM 32
#define TB (T_DIM*B_DIM)   // 131072

typedef unsigned short u16;
typedef unsigned int   u32;
typedef _Float16 half2v __attribute__((ext_vector_type(2)));
typedef __attribute__((ext_vector_type(8))) short short8;   // 8 bf16 (4 VGPRs)
typedef __attribute__((ext_vector_type(4))) float f32x4;
typedef __attribute__((ext_vector_type(4))) u32   u32x4;

__device__ __forceinline__ float bf2f(u16 v){ return __uint_as_float(((u32)v)<<16); }
__device__ __forceinline__ u16 f2bf(float f){
    u32 x = __float_as_uint(f);
    u32 r = x + 0x7fffu + ((x>>16)&1u);   // round-to-nearest-even
    return (u16)(r>>16);
}
__device__ __forceinline__ float2 bfpair(u32 u){
    return make_float2(__uint_as_float(u<<16), __uint_as_float(u & 0xffff0000u));
}

// packed-f16-pair dot: acc += a.lo*b.lo + a.hi*b.hi
__device__ __forceinline__ float dot2(u32 a, u32 b, float c){
#if __has_builtin(__builtin_amdgcn_fdot2)
    return __builtin_amdgcn_fdot2(__builtin_bit_cast(half2v,a),
                                  __builtin_bit_cast(half2v,b), c, false);
#else
    half2v ha = __builtin_bit_cast(half2v,a), hb = __builtin_bit_cast(half2v,b);
    return fmaf((float)ha[0],(float)hb[0], fmaf((float)ha[1],(float)hb[1], c));
#endif
}

// ---------------------------------------------------------------------------
// dones dtype probe (u8 bool vs i32 vs f32) via nonzero byte positions mod 4.
// ---------------------------------------------------------------------------
__global__ void zero_flags_kernel(int* p){ if(threadIdx.x<4) p[threadIdx.x]=0; }

__global__ void detect_kernel(const unsigned char* __restrict__ d, int n, int* __restrict__ flags){
    int f=0;
    for(int p = blockIdx.x*blockDim.x+threadIdx.x; p<n; p += gridDim.x*blockDim.x){
        if(d[p]){ int m=p&3; if(m==1) f|=1; else if(m>=2) f|=2; }
    }
    if(f) atomicOr(flags, f);
}

// concat b_a1(256) | b_c1(256) -> b_ac(512) for the fused head-1 GEMM
__global__ void concat_bias_kernel(const float* __restrict__ a, const float* __restrict__ b,
                                   float* __restrict__ dst){
    int i = threadIdx.x;
    dst[i] = a[i];
    dst[256 + i] = b[i];
}

// ---------------------------------------------------------------------------
// Recurrent weights -> packed f16 pairs: dst[((m*32+q)*256 + j)*4 + e] packs
// k=2*(4q+e), 2*(4q+e)+1 of column j of matrix m (q covers k=8q..8q+7).
// ---------------------------------------------------------------------------
__global__ void cvt_wt_kernel(const float* __restrict__ Whr, const float* __restrict__ Whz,
                              const float* __restrict__ Whn, u32* __restrict__ dst){
    int i = blockIdx.x*blockDim.x + threadIdx.x;
    if(i >= 3*32*256*4) return;
    int e = i & 3;
    int j = (i >> 2) & 255;
    int q = (i >> 10) & 31;
    int m = i >> 15;
    const float* W = (m==0) ? Whr : (m==1) ? Whz : Whn;
    int kp = q*4 + e, k = 2*kp;
    _Float16 lo = (_Float16)W[(size_t)k    *H_DIM + j];
    _Float16 hi = (_Float16)W[(size_t)(k+1)*H_DIM + j];
    dst[i] = (u32)__builtin_bit_cast(u16,lo) | ((u32)__builtin_bit_cast(u16,hi) << 16);
}

// GEMM weight f32 [K][N] -> bf16 transposed [N][K]
__global__ void cvt_wT_kernel(const float* __restrict__ W, u16* __restrict__ dst,
                              int K, int N){
    int i = blockIdx.x*blockDim.x + threadIdx.x;
    if(i >= K*N) return;
    int n = i / K;
    int k = i - n*K;
    dst[i] = f2bf(W[(size_t)k*N + n]);
}

// ---------------------------------------------------------------------------
// MFMA bf16 GEMM: C[M,N](bf16) = opt_relu(A @ Bt^T + bias), Bt bf16 [N][K].
// A is bf16 (AF32=0) or f32 converted during staging (AF32=1).
// 128x128 tile, BK=32, 4 waves 2x2, 16x mfma_f32_16x16x32_bf16 each.
// ---------------------------------------------------------------------------
template<int RELU, int AF32>
__global__ __launch_bounds__(256, 2)
void gemm_mfma_kernel(const void* __restrict__ A_, const u16* __restrict__ Bt,
                      const float* __restrict__ bias, u16* __restrict__ C,
                      int M, int N, int K)
{
    __shared__ u16 As[128*32];
    __shared__ u16 Bs[128*32];
    const int tid  = threadIdx.x;
    const int wave = tid >> 6;
    const int lane = tid & 63;
    const int ln15 = lane & 15;
    const int quad = lane >> 4;
    const int wm = wave & 1, wn = wave >> 1;
    const int rowBase = blockIdx.y*128;
    const int colBase = blockIdx.x*128;

    f32x4 acc[4][4] = {};

    const int sr = tid >> 1;
    const int sc = (tid & 1) * 16;

    for(int kb = 0; kb < K; kb += 32){
        if(AF32){
            const float* af = (const float*)A_;
            const float* ag = af + (size_t)(rowBase+sr)*K + kb + sc;
            float4 f0 = *(const float4*)ag;
            float4 f1 = *(const float4*)(ag+4);
            float4 f2 = *(const float4*)(ag+8);
            float4 f3 = *(const float4*)(ag+12);
            u16 tmp[16] = { f2bf(f0.x),f2bf(f0.y),f2bf(f0.z),f2bf(f0.w),
                            f2bf(f1.x),f2bf(f1.y),f2bf(f1.z),f2bf(f1.w),
                            f2bf(f2.x),f2bf(f2.y),f2bf(f2.z),f2bf(f2.w),
                            f2bf(f3.x),f2bf(f3.y),f2bf(f3.z),f2bf(f3.w) };
            *(uint4*)&As[sr*32 + sc]     = *(const uint4*)&tmp[0];
            *(uint4*)&As[sr*32 + sc + 8] = *(const uint4*)&tmp[8];
        } else {
            const u16* ab = (const u16*)A_;
            const u16* ag = ab + (size_t)(rowBase+sr)*K + kb + sc;
            uint4 av0 = *(const uint4*)ag;
            uint4 av1 = *(const uint4*)(ag+8);
            *(uint4*)&As[sr*32 + sc]     = av0;
            *(uint4*)&As[sr*32 + sc + 8] = av1;
        }
        {
            const u16* bg = Bt + (size_t)(colBase+sr)*K + kb + sc;
            uint4 bv0 = *(const uint4*)bg;
            uint4 bv1 = *(const uint4*)(bg+8);
            *(uint4*)&Bs[sr*32 + sc]     = bv0;
            *(uint4*)&Bs[sr*32 + sc + 8] = bv1;
        }
        __syncthreads();

        short8 af[4], bf[4];
        #pragma unroll
        for(int mt=0;mt<4;mt++)
            af[mt] = *(const short8*)&As[(wm*64+mt*16+ln15)*32 + quad*8];
        #pragma unroll
        for(int nt=0;nt<4;nt++)
            bf[nt] = *(const short8*)&Bs[(wn*64+nt*16+ln15)*32 + quad*8];
        #pragma unroll
        for(int mt=0;mt<4;mt++){
            #pragma unroll
            for(int nt=0;nt<4;nt++){
                acc[mt][nt] = __builtin_amdgcn_mfma_f32_16x16x32_bf16(
                                  af[mt], bf[nt], acc[mt][nt], 0, 0, 0);
            }
        }
        __syncthreads();
    }

    #pragma unroll
    for(int nt=0;nt<4;nt++){
        int n = colBase + wn*64 + nt*16 + ln15;
        float bv = bias[n];
        #pragma unroll
        for(int mt=0;mt<4;mt++){
            #pragma unroll
            for(int r=0;r<4;r++){
                int m = rowBase + wm*64 + mt*16 + quad*4 + r;
                float v = acc[mt][nt][r] + bv;
                if(RELU) v = fmaxf(v, 0.f);
                C[(size_t)m*N + n] = f2bf(v);
            }
        }
    }
}

// ---------------------------------------------------------------------------
// GRU scan v6 = R2 (best measured: 94us/chunk) + redundant all-thread gates.
// 256 blocks (one batch row) x 1024 threads. Thread (g=tid>>8 k-quarter,
// j=tid&255 column) owns k-range [64g,64g+64) of column j, all 3 matrices
// (96 packed-f16 u32, pinned; the allocator WILL park these in AGPRs and pay
// 1 v_accvgpr_read per use -- R2/R3/R5 proved this is unavoidable at source
// level; the tax is ~768cyc/SIMD/step and is accepted).
// R2's remaining stall (~1375cyc/step): gate phase ran on g==0 only -> 12 of
// 16 waves idled behind a 1-wave serial chain. v6: ALL threads read the 12
// partials (rex is slot-major [12][256] f32: stride-1 across lanes,
// conflict-free both ways) and compute the gates redundantly; only g==0
// commits y/hbuf/h_carry. gi/dones loads per-thread (same addr across g ->
// L1 broadcast). Both barriers now separate all-wave phases; no idle tail.
// ---------------------------------------------------------------------------
__global__ __attribute__((amdgpu_flat_work_group_size(1024,1024), amdgpu_waves_per_eu(4,4)))
void scan_kernel(const u16* __restrict__ gi, const void* __restrict__ dones,
                 const int* __restrict__ flags, const u32x4* __restrict__ Wt4,
                 const float* __restrict__ bhn, float* __restrict__ h_carry,
                 u16* __restrict__ y, int t0, int Tc)
{
    __shared__ __align__(16) u32 hbuf[2][128];   // 256 packed f16 each
    __shared__ float rex[12][256];               // slot-major partials (m*4+g)
    const int tid = threadIdx.x;
    const int j   = tid & 255;
    const int g   = tid >> 8;      // k-quarter 0..3
    const int row = blockIdx.x;
    const int fl  = flags[0];
    const int mode = (fl&1) ? 0 : ((fl&2) ? 2 : 1);  // 0=u8, 1=i32, 2=f32

    auto getdone = [&](int t)->bool{
        int idx = t*B_DIM + row;
        if(mode==0) return ((const unsigned char*)dones)[idx] != 0;
        if(mode==1) return ((const int*)dones)[idx] != 0;
        return ((const float*)dones)[idx] != 0.f;
    };

    // ---- one-time weight load: k-quarter g of column j, all three mats ----
    const u32x4* baseR = Wt4 + (size_t)( 0 + g*8)*256 + j;
    const u32x4* baseZ = Wt4 + (size_t)(32 + g*8)*256 + j;
    const u32x4* baseN = Wt4 + (size_t)(64 + g*8)*256 + j;
    u32 wr[32], wz[32], wn[32];
    #pragma unroll
    for(int q=0;q<8;q++){
        u32x4 tr = baseR[(size_t)q*256]; wr[4*q]=tr[0]; wr[4*q+1]=tr[1]; wr[4*q+2]=tr[2]; wr[4*q+3]=tr[3];
        u32x4 tz = baseZ[(size_t)q*256]; wz[4*q]=tz[0]; wz[4*q+1]=tz[1]; wz[4*q+2]=tz[2]; wz[4*q+3]=tz[3];
        u32x4 tn = baseN[(size_t)q*256]; wn[4*q]=tn[0]; wn[4*q+1]=tn[1]; wn[4*q+2]=tn[2]; wn[4*q+3]=tn[3];
    }
    #pragma unroll
    for(int q=0;q<32;q+=4){
        asm volatile("" : "+v"(wr[q  ]),"+v"(wr[q+1]),"+v"(wr[q+2]),"+v"(wr[q+3]),
                          "+v"(wz[q  ]),"+v"(wz[q+1]),"+v"(wz[q+2]),"+v"(wz[q+3]),
                          "+v"(wn[q  ]),"+v"(wn[q+1]),"+v"(wn[q+2]),"+v"(wn[q+3]));
    }

    const float bh = bhn[j];
    float hoj;
    {
        bool d0 = getdone(t0);
        hoj = d0 ? 0.f : h_carry[(size_t)row*H_DIM + j];   // redundant across g
        if(g == 0) ((_Float16*)hbuf[0])[j] = (_Float16)hoj;
    }
    __syncthreads();

    int cur = 0;
    for(int t=0; t<Tc; ++t){
        // per-thread gate-input loads (same addr across g -> L1 broadcast);
        // latency hides under the dot phase
        size_t gbase = ((size_t)t*B_DIM + row)*768;
        float ir  = bf2f(gi[gbase + j]);
        float izv = bf2f(gi[gbase + 256 + j]);
        float inn = bf2f(gi[gbase + 512 + j]);
        bool  dn  = (t < Tc-1) ? getdone(t0+t+1) : false;

        // partial dots over this thread's k-quarter, all three matrices.
        // hv is a wave-uniform broadcast read, reused across r/z/n.
        float r0=0.f,r1=0.f,z0=0.f,z1=0.f,n0=0.f,n1=0.f;
        const u32x4* hb = (const u32x4*)hbuf[cur] + g*8;
        #pragma unroll
        for(int q=0;q<8;q++){
            u32x4 hv = hb[q];
            r0 = dot2(wr[4*q  ], hv[0], r0); r1 = dot2(wr[4*q+1], hv[1], r1);
            r0 = dot2(wr[4*q+2], hv[2], r0); r1 = dot2(wr[4*q+3], hv[3], r1);
            z0 = dot2(wz[4*q  ], hv[0], z0); z1 = dot2(wz[4*q+1], hv[1], z1);
            z0 = dot2(wz[4*q+2], hv[2], z0); z1 = dot2(wz[4*q+3], hv[3], z1);
            n0 = dot2(wn[4*q  ], hv[0], n0); n1 = dot2(wn[4*q+1], hv[1], n1);
            n0 = dot2(wn[4*q+2], hv[2], n0); n1 = dot2(wn[4*q+3], hv[3], n1);
        }
        rex[g  ][j] = r0 + r1;
        rex[4+g][j] = z0 + z1;
        rex[8+g][j] = n0 + n1;
        __syncthreads();

        // ---- redundant gate phase: all 16 waves work, no idle tail ----
        float rt = (rex[0][j] + rex[1][j]) + (rex[2][j]  + rex[3][j]);
        float zt = (rex[4][j] + rex[5][j]) + (rex[6][j]  + rex[7][j]);
        float nt = (rex[8][j] + rex[9][j]) + (rex[10][j] + rex[11][j]);
        float r = 1.f/(1.f + __expf(-(ir  + rt)));
        float z = 1.f/(1.f + __expf(-(izv + zt)));
        float x = inn + r*(nt + bh);
        float e2 = __expf(2.f*x);
        float n = 1.f - 2.f/(e2 + 1.f);          // tanh(x)
        float hn = (1.f - z)*n + z*hoj;
        hoj = dn ? 0.f : hn;                     // dn=false on last chunk step
        if(g == 0){
            y[((size_t)t*B_DIM + row)*H_DIM + j] = f2bf(hn);
            ((_Float16*)hbuf[cur^1])[j] = (_Float16)hoj;
        }
        __syncthreads();
        cur ^= 1;
    }

    if(g == 0) h_carry[(size_t)row*H_DIM + j] = hoj;  // raw carry
}

// ---------------------------------------------------------------------------
// Actor head stage 2: logits[rows,32] = ah[rows,:256 of ld] @ W_a2 + b_a2 - (1-avail)*1e10
// ---------------------------------------------------------------------------
__global__ __launch_bounds__(256)
void actor2_kernel(const u16* __restrict__ ah, int ld, const float* __restrict__ W_a2,
                   const float* __restrict__ b_a2, const float* __restrict__ avail,
                   float* __restrict__ logits)
{
    __shared__ u16 ahs[64][264];
    const int tid = threadIdx.x;
    const int r0 = blockIdx.x*64;
    {
        int row = tid & 63;
        int c0 = (tid >> 6) * 64;
        const uint4* gp = (const uint4*)(ah + (size_t)(r0+row)*ld + c0);
        #pragma unroll
        for(int q=0;q<8;q++){
            uint4 u = gp[q];
            u32* dst = (u32*)&ahs[row][c0 + q*8];
            dst[0]=u.x; dst[1]=u.y; dst[2]=u.z; dst[3]=u.w;
        }
    }
    __syncthreads();
    const int c  = tid & 31;
    const int rg = tid >> 5;   // 0..7
    float acc[8]={0.f,0.f,0.f,0.f,0.f,0.f,0.f,0.f};
    float bc = b_a2[c];
    for(int k=0;k<H_DIM;k+=4){
        float w0 = W_a2[(k+0)*A_DIM + c];
        float w1 = W_a2[(k+1)*A_DIM + c];
        float w2 = W_a2[(k+2)*A_DIM + c];
        float w3 = W_a2[(k+3)*A_DIM + c];
        #pragma unroll
        for(int rr=0;rr<8;rr++){
            uint2 av = *(const uint2*)&ahs[rg*8+rr][k];
            float2 p0 = bfpair(av.x), p1 = bfpair(av.y);
            acc[rr] = fmaf(p0.x,w0,fmaf(p0.y,w1,fmaf(p1.x,w2,fmaf(p1.y,w3,acc[rr]))));
        }
    }
    #pragma unroll
    for(int rr=0;rr<8;rr++){
        int grow = r0 + rg*8 + rr;
        float av = avail[(size_t)grow*A_DIM + c];
        logits[(size_t)grow*A_DIM + c] = acc[rr] + bc - (1.f-av)*1e10f;
    }
}

// ---------------------------------------------------------------------------
// Critic head stage 2: value[row] = ch[row,:256 of ld] @ W_c2 + b_c2. Wave per row.
// ---------------------------------------------------------------------------
__global__ __launch_bounds__(256)
void critic2_kernel(const u16* __restrict__ ch, int ld, const float* __restrict__ W_c2,
                    const float* __restrict__ b_c2, float* __restrict__ value)
{
    const int lane = threadIdx.x & 63;
    const int wid  = threadIdx.x >> 6;
    const int row  = blockIdx.x*4 + wid;
    uint2 av = *(const uint2*)(ch + (size_t)row*ld + lane*4);
    float2 p0 = bfpair(av.x), p1 = bfpair(av.y);
    float4 wv = *(const float4*)(W_c2 + lane*4);
    float acc = p0.x*wv.x + p0.y*wv.y + p1.x*wv.z + p1.y*wv.w;
    #pragma unroll
    for(int off=32; off>0; off>>=1) acc += __shfl_down(acc, off, 64);
    if(lane==0) value[row] = acc + b_c2[0];
}

// ---------------------------------------------------------------------------
extern "C" void kernel_launch(void* const* d_in, const int* in_sizes, int n_in,
                              void* d_out, int out_size, void* d_ws, size_t ws_size,
                              hipStream_t stream)
{
    const float* hidden = (const float*)d_in[0];
    const float* obs    = (const float*)d_in[1];
    const void*  dones  = d_in[2];
    const float* avail  = (const float*)d_in[3];
    const float* W_emb  = (const float*)d_in[4];
    const float* b_emb  = (const float*)d_in[5];
    const float* Wi     = (const float*)d_in[6];
    const float* bi     = (const float*)d_in[7];
    const float* Whr    = (const float*)d_in[8];
    const float* Whz    = (const float*)d_in[9];
    const float* Whn    = (const float*)d_in[10];
    const float* bhn    = (const float*)d_in[11];
    const float* W_a1   = (const float*)d_in[12];
    const float* b_a1   = (const float*)d_in[13];
    const float* W_a2   = (const float*)d_in[14];
    const float* b_a2   = (const float*)d_in[15];
    const float* W_c1   = (const float*)d_in[16];
    const float* b_c1   = (const float*)d_in[17];
    const float* W_c2   = (const float*)d_in[18];
    const float* b_c2   = (const float*)d_in[19];

    float* out_hidden = (float*)d_out;                       // 65536
    float* out_logits = out_hidden + (size_t)B_DIM*H_DIM;    // 4194304
    float* out_value  = out_logits + (size_t)TB*A_DIM;       // 131072

    // ---- workspace layout (chunk size adapted to ws_size, deterministic) ----
    // fixed: wt_b + wiT + wacT(fused a1|c1) + wembT + h_carry + flags + b_ac
    const size_t fixed = 393216 + 393216 + 262144 + 65536 + 262144 + 256 + 2048;
    int Tc = 4;
    for(int cand = 64; cand >= 4; cand >>= 1){
        size_t need = fixed + (size_t)cand*(393216 /*gi*/ + 262144 /*emb|ac*/ + 131072 /*y*/);
        if(need <= ws_size){ Tc = cand; break; }
    }
    const int NC = T_DIM / Tc;

    uint8_t* ws = (uint8_t*)d_ws;
    size_t off = 0;
    u32*  wt_b    = (u32*)(ws + off); off += 393216;   // scan weights, packed f16
    u16*  wiT     = (u16*)(ws + off); off += 393216;   // Wi^T bf16 [768][256]
    u16*  wacT    = (u16*)(ws + off); off += 262144;   // [W_a1^T | W_c1^T] bf16 [512][256]
    u16*  wembT   = (u16*)(ws + off); off += 65536;    // W_emb^T bf16 [256][128]
    float* h_carry= (float*)(ws + off); off += 262144;
    int*  flags   = (int*)(ws + off); off += 256;
    float* b_ac   = (float*)(ws + off); off += 2048;   // b_a1|b_c1 (512 f32)
    u16*  gi_c    = (u16*)(ws + off); off += (size_t)Tc*393216;
    u16*  embac_c = (u16*)(ws + off); off += (size_t)Tc*262144;  // emb [Mc][256], later ac [Mc][512]
    u16*  y_c     = (u16*)(ws + off); off += (size_t)Tc*131072;
    u16*  emb_c   = embac_c;
    u16*  ac_c    = embac_c;

    zero_flags_kernel<<<1, 64, 0, stream>>>(flags);
    detect_kernel<<<64, 256, 0, stream>>>((const unsigned char*)dones, TB, flags);
    cvt_wt_kernel<<<384, 256, 0, stream>>>(Whr, Whz, Whn, wt_b);
    cvt_wT_kernel<<<768, 256, 0, stream>>>(Wi,   wiT,  256, 768);
    cvt_wT_kernel<<<256, 256, 0, stream>>>(W_a1, wacT,          256, 256);
    cvt_wT_kernel<<<256, 256, 0, stream>>>(W_c1, wacT + 65536,  256, 256);
    cvt_wT_kernel<<<128, 256, 0, stream>>>(W_emb, wembT, 128, 256);
    concat_bias_kernel<<<1, 256, 0, stream>>>(b_a1, b_c1, b_ac);
    hipMemcpyAsync(h_carry, hidden, (size_t)B_DIM*H_DIM*sizeof(float),
                   hipMemcpyDeviceToDevice, stream);

    const int Mc = Tc*B_DIM;
    const int gy = Mc/128;

    for(int c = 0; c < NC; ++c){
        const int t0 = c*Tc;
        const float* obs_c = obs + (size_t)t0*B_DIM*OBS_DIM;
        // emb = relu(obs @ W_emb + b_emb)  (MFMA, f32 A converted in staging)
        gemm_mfma_kernel<1,1><<<dim3(2,gy), 256, 0, stream>>>(obs_c, wembT, b_emb, emb_c, Mc, 256, 128);
        // gi = emb @ Wi + bi  (MFMA)
        gemm_mfma_kernel<0,0><<<dim3(6,gy), 256, 0, stream>>>(emb_c, wiT, bi, gi_c, Mc, 768, 256);
        // GRU scan chunk: 256 blocks (one per batch row) x 1024 threads
        scan_kernel<<<256, 1024, 0, stream>>>(gi_c, dones, flags, (const u32x4*)wt_b,
                                              bhn, h_carry, y_c, t0, Tc);
        // fused actor1|critic1 head: [Mc][512] = relu(y @ [W_a1|W_c1] + b_ac)
        gemm_mfma_kernel<1,0><<<dim3(4,gy), 256, 0, stream>>>(y_c, wacT, b_ac, ac_c, Mc, 512, 256);
        actor2_kernel<<<Mc/64, 256, 0, stream>>>(ac_c, 512, W_a2, b_a2,
                                                 avail + (size_t)t0*B_DIM*A_DIM,
                                                 out_logits + (size_t)t0*B_DIM*A_DIM);
        critic2_kernel<<<Mc/4, 256, 0, stream>>>(ac_c + 256, 512, W_c2, b_c2,
                                                 out_value + (size_t)t0*B_DIM);
    }

    hipMemcpyAsync(out_hidden, h_carry, (size_t)B_DIM*H_DIM*sizeof(float),
                   hipMemcpyDeviceToDevice, stream);
}

// Round 7
// 1345.038 us; speedup vs baseline: 1.4536x; 1.2154x over previous
//
#include <hip/hip_runtime.h>
#include <stdint.h>

#define T_DIM 512
#define B_DIM 256
#define OBS_DIM 128
#define H_DIM 256
#define A_DIM 32
#define TB (T_DIM*B_DIM)   // 131072

typedef unsigned short u16;
typedef unsigned int   u32;
typedef _Float16 half2v __attribute__((ext_vector_type(2)));
typedef __attribute__((ext_vector_type(8))) short short8;   // 8 bf16 (4 VGPRs)
typedef __attribute__((ext_vector_type(4))) float f32x4;
typedef __attribute__((ext_vector_type(4))) u32   u32x4;

__device__ __forceinline__ float bf2f(u16 v){ return __uint_as_float(((u32)v)<<16); }
__device__ __forceinline__ u16 f2bf(float f){
    u32 x = __float_as_uint(f);
    u32 r = x + 0x7fffu + ((x>>16)&1u);   // round-to-nearest-even
    return (u16)(r>>16);
}
__device__ __forceinline__ float2 bfpair(u32 u){
    return make_float2(__uint_as_float(u<<16), __uint_as_float(u & 0xffff0000u));
}

// packed-f16-pair dot: acc += a.lo*b.lo + a.hi*b.hi
__device__ __forceinline__ float dot2(u32 a, u32 b, float c){
#if __has_builtin(__builtin_amdgcn_fdot2)
    return __builtin_amdgcn_fdot2(__builtin_bit_cast(half2v,a),
                                  __builtin_bit_cast(half2v,b), c, false);
#else
    half2v ha = __builtin_bit_cast(half2v,a), hb = __builtin_bit_cast(half2v,b);
    return fmaf((float)ha[0],(float)hb[0], fmaf((float)ha[1],(float)hb[1], c));
#endif
}

// inline-asm dot2: forces all operands into ARCH VGPRs at every use site.
// (VOP3P can't read AGPRs; the intrinsic path let the allocator park the
// weight arrays in AGPRs and pay one v_accvgpr_read per use -- R2/R3/R5.)
#define DOT2A(acc, w, h) \
    asm("v_dot2_f32_f16 %0, %1, %2, %0" : "+v"(acc) : "v"(w), "v"(h))

// ---------------------------------------------------------------------------
// dones dtype probe (u8 bool vs i32 vs f32) via nonzero byte positions mod 4.
// ---------------------------------------------------------------------------
__global__ void zero_flags_kernel(int* p){ if(threadIdx.x<4) p[threadIdx.x]=0; }

__global__ void detect_kernel(const unsigned char* __restrict__ d, int n, int* __restrict__ flags){
    int f=0;
    for(int p = blockIdx.x*blockDim.x+threadIdx.x; p<n; p += gridDim.x*blockDim.x){
        if(d[p]){ int m=p&3; if(m==1) f|=1; else if(m>=2) f|=2; }
    }
    if(f) atomicOr(flags, f);
}

// concat b_a1(256) | b_c1(256) -> b_ac(512) for the fused head-1 GEMM
__global__ void concat_bias_kernel(const float* __restrict__ a, const float* __restrict__ b,
                                   float* __restrict__ dst){
    int i = threadIdx.x;
    dst[i] = a[i];
    dst[256 + i] = b[i];
}

// ---------------------------------------------------------------------------
// Recurrent weights -> packed f16 pairs: dst[((m*32+q)*256 + j)*4 + e] packs
// k=2*(4q+e), 2*(4q+e)+1 of column j of matrix m (q covers k=8q..8q+7).
// ---------------------------------------------------------------------------
__global__ void cvt_wt_kernel(const float* __restrict__ Whr, const float* __restrict__ Whz,
                              const float* __restrict__ Whn, u32* __restrict__ dst){
    int i = blockIdx.x*blockDim.x + threadIdx.x;
    if(i >= 3*32*256*4) return;
    int e = i & 3;
    int j = (i >> 2) & 255;
    int q = (i >> 10) & 31;
    int m = i >> 15;
    const float* W = (m==0) ? Whr : (m==1) ? Whz : Whn;
    int kp = q*4 + e, k = 2*kp;
    _Float16 lo = (_Float16)W[(size_t)k    *H_DIM + j];
    _Float16 hi = (_Float16)W[(size_t)(k+1)*H_DIM + j];
    dst[i] = (u32)__builtin_bit_cast(u16,lo) | ((u32)__builtin_bit_cast(u16,hi) << 16);
}

// GEMM weight f32 [K][N] -> bf16 transposed [N][K]
__global__ void cvt_wT_kernel(const float* __restrict__ W, u16* __restrict__ dst,
                              int K, int N){
    int i = blockIdx.x*blockDim.x + threadIdx.x;
    if(i >= K*N) return;
    int n = i / K;
    int k = i - n*K;
    dst[i] = f2bf(W[(size_t)k*N + n]);
}

// ---------------------------------------------------------------------------
// MFMA bf16 GEMM: C[M,N](bf16) = opt_relu(A @ Bt^T + bias), Bt bf16 [N][K].
// A is bf16 (AF32=0) or f32 converted during staging (AF32=1).
// 128x128 tile, BK=32, 4 waves 2x2, 16x mfma_f32_16x16x32_bf16 each.
// ---------------------------------------------------------------------------
template<int RELU, int AF32>
__global__ __launch_bounds__(256, 2)
void gemm_mfma_kernel(const void* __restrict__ A_, const u16* __restrict__ Bt,
                      const float* __restrict__ bias, u16* __restrict__ C,
                      int M, int N, int K)
{
    __shared__ u16 As[128*32];
    __shared__ u16 Bs[128*32];
    const int tid  = threadIdx.x;
    const int wave = tid >> 6;
    const int lane = tid & 63;
    const int ln15 = lane & 15;
    const int quad = lane >> 4;
    const int wm = wave & 1, wn = wave >> 1;
    const int rowBase = blockIdx.y*128;
    const int colBase = blockIdx.x*128;

    f32x4 acc[4][4] = {};

    const int sr = tid >> 1;
    const int sc = (tid & 1) * 16;

    for(int kb = 0; kb < K; kb += 32){
        if(AF32){
            const float* af = (const float*)A_;
            const float* ag = af + (size_t)(rowBase+sr)*K + kb + sc;
            float4 f0 = *(const float4*)ag;
            float4 f1 = *(const float4*)(ag+4);
            float4 f2 = *(const float4*)(ag+8);
            float4 f3 = *(const float4*)(ag+12);
            u16 tmp[16] = { f2bf(f0.x),f2bf(f0.y),f2bf(f0.z),f2bf(f0.w),
                            f2bf(f1.x),f2bf(f1.y),f2bf(f1.z),f2bf(f1.w),
                            f2bf(f2.x),f2bf(f2.y),f2bf(f2.z),f2bf(f2.w),
                            f2bf(f3.x),f2bf(f3.y),f2bf(f3.z),f2bf(f3.w) };
            *(uint4*)&As[sr*32 + sc]     = *(const uint4*)&tmp[0];
            *(uint4*)&As[sr*32 + sc + 8] = *(const uint4*)&tmp[8];
        } else {
            const u16* ab = (const u16*)A_;
            const u16* ag = ab + (size_t)(rowBase+sr)*K + kb + sc;
            uint4 av0 = *(const uint4*)ag;
            uint4 av1 = *(const uint4*)(ag+8);
            *(uint4*)&As[sr*32 + sc]     = av0;
            *(uint4*)&As[sr*32 + sc + 8] = av1;
        }
        {
            const u16* bg = Bt + (size_t)(colBase+sr)*K + kb + sc;
            uint4 bv0 = *(const uint4*)bg;
            uint4 bv1 = *(const uint4*)(bg+8);
            *(uint4*)&Bs[sr*32 + sc]     = bv0;
            *(uint4*)&Bs[sr*32 + sc + 8] = bv1;
        }
        __syncthreads();

        short8 af[4], bf[4];
        #pragma unroll
        for(int mt=0;mt<4;mt++)
            af[mt] = *(const short8*)&As[(wm*64+mt*16+ln15)*32 + quad*8];
        #pragma unroll
        for(int nt=0;nt<4;nt++)
            bf[nt] = *(const short8*)&Bs[(wn*64+nt*16+ln15)*32 + quad*8];
        #pragma unroll
        for(int mt=0;mt<4;mt++){
            #pragma unroll
            for(int nt=0;nt<4;nt++){
                acc[mt][nt] = __builtin_amdgcn_mfma_f32_16x16x32_bf16(
                                  af[mt], bf[nt], acc[mt][nt], 0, 0, 0);
            }
        }
        __syncthreads();
    }

    #pragma unroll
    for(int nt=0;nt<4;nt++){
        int n = colBase + wn*64 + nt*16 + ln15;
        float bv = bias[n];
        #pragma unroll
        for(int mt=0;mt<4;mt++){
            #pragma unroll
            for(int r=0;r<4;r++){
                int m = rowBase + wm*64 + mt*16 + quad*4 + r;
                float v = acc[mt][nt][r] + bv;
                if(RELU) v = fmaxf(v, 0.f);
                C[(size_t)m*N + n] = f2bf(v);
            }
        }
    }
}

// ---------------------------------------------------------------------------
// GRU scan v7 = R2-exact structure (best measured, 94.6us/chunk) with the
// dot2 intrinsic replaced by inline-asm v_dot2_f32_f16 ("v" operand class)
// and the 96-operand pin-asm REMOVED.
// Rationale: R2/R3/R5 showed the allocator parks pinned weight arrays in
// AGPRs regardless of demand (VGPR_Count 64/52/224), taxing every VOP3P dot
// with a v_accvgpr_read (~770cyc/SIMD/step). R6 showed the gate tail is NOT
// the stall (redundant gates cost +37us). Theory: the pin-asm's simultaneous
// 96-operand arch-class pressure spike marks the weights as spill candidates;
// per-use "v" asm constraints + no spike keeps arch demand ~126 <= the
// 128-reg budget of the (4,4) clamp with live ranges the allocator can only
// satisfy in arch regs or by explicit per-use copies (what we have now, so
// worst case = status quo).
// 256 blocks (one batch row) x 1024 threads; thread (g=k-quarter, j=column)
// owns k-range [64g,64g+64) of column j, all 3 matrices; g0 computes gates.
// ---------------------------------------------------------------------------
__global__ __attribute__((amdgpu_flat_work_group_size(1024,1024), amdgpu_waves_per_eu(4,4)))
void scan_kernel(const u16* __restrict__ gi, const void* __restrict__ dones,
                 const int* __restrict__ flags, const u32x4* __restrict__ Wt4,
                 const float* __restrict__ bhn, float* __restrict__ h_carry,
                 u16* __restrict__ y, int t0, int Tc)
{
    __shared__ __align__(16) u32 hbuf[2][128];   // 256 packed f16 each
    __shared__ float rex[3][4][256];             // partial dots per mat/quarter
    const int tid = threadIdx.x;
    const int j   = tid & 255;
    const int g   = tid >> 8;      // k-quarter 0..3
    const int row = blockIdx.x;
    const int fl  = flags[0];
    const int mode = (fl&1) ? 0 : ((fl&2) ? 2 : 1);  // 0=u8, 1=i32, 2=f32

    auto getdone = [&](int t)->bool{
        int idx = t*B_DIM + row;
        if(mode==0) return ((const unsigned char*)dones)[idx] != 0;
        if(mode==1) return ((const int*)dones)[idx] != 0;
        return ((const float*)dones)[idx] != 0.f;
    };

    // ---- one-time weight load: k-quarter g of column j, all three mats ----
    const u32x4* baseR = Wt4 + (size_t)( 0 + g*8)*256 + j;
    const u32x4* baseZ = Wt4 + (size_t)(32 + g*8)*256 + j;
    const u32x4* baseN = Wt4 + (size_t)(64 + g*8)*256 + j;
    u32 wr[32], wz[32], wn[32];
    #pragma unroll
    for(int q=0;q<8;q++){
        u32x4 tr = baseR[(size_t)q*256]; wr[4*q]=tr[0]; wr[4*q+1]=tr[1]; wr[4*q+2]=tr[2]; wr[4*q+3]=tr[3];
        u32x4 tz = baseZ[(size_t)q*256]; wz[4*q]=tz[0]; wz[4*q+1]=tz[1]; wz[4*q+2]=tz[2]; wz[4*q+3]=tz[3];
        u32x4 tn = baseN[(size_t)q*256]; wn[4*q]=tn[0]; wn[4*q+1]=tn[1]; wn[4*q+2]=tn[2]; wn[4*q+3]=tn[3];
    }
    // NOTE: no pin-asm here (see header comment).

    const float bh = bhn[j];
    float hoj = 0.f;
    if(g == 0){
        bool d0 = getdone(t0);
        hoj = d0 ? 0.f : h_carry[(size_t)row*H_DIM + j];
        ((_Float16*)hbuf[0])[j] = (_Float16)hoj;
    }
    __syncthreads();

    int cur = 0;
    for(int t=0; t<Tc; ++t){
        // gate-input loads up front (latency hides under the dot phase)
        size_t gbase = ((size_t)t*B_DIM + row)*768;
        float ir=0.f, izv=0.f, inn=0.f; bool dn=false;
        if(g == 0){
            ir  = bf2f(gi[gbase + j]);
            izv = bf2f(gi[gbase + 256 + j]);
            inn = bf2f(gi[gbase + 512 + j]);
            dn  = (t < Tc-1) ? getdone(t0+t+1) : false;
        }

        // partial dots over this thread's k-quarter, all three matrices.
        // hv is a wave-uniform broadcast read, reused across r/z/n.
        float r0=0.f,r1=0.f,z0=0.f,z1=0.f,n0=0.f,n1=0.f;
        const u32x4* hb = (const u32x4*)hbuf[cur] + g*8;
        #pragma unroll
        for(int q=0;q<8;q++){
            u32x4 hv = hb[q];
            DOT2A(r0, wr[4*q  ], hv[0]); DOT2A(r1, wr[4*q+1], hv[1]);
            DOT2A(r0, wr[4*q+2], hv[2]); DOT2A(r1, wr[4*q+3], hv[3]);
            DOT2A(z0, wz[4*q  ], hv[0]); DOT2A(z1, wz[4*q+1], hv[1]);
            DOT2A(z0, wz[4*q+2], hv[2]); DOT2A(z1, wz[4*q+3], hv[3]);
            DOT2A(n0, wn[4*q  ], hv[0]); DOT2A(n1, wn[4*q+1], hv[1]);
            DOT2A(n0, wn[4*q+2], hv[2]); DOT2A(n1, wn[4*q+3], hv[3]);
        }
        rex[0][g][j] = r0 + r1;
        rex[1][g][j] = z0 + z1;
        rex[2][g][j] = n0 + n1;
        __syncthreads();

        if(g == 0){
            float rt = (rex[0][0][j] + rex[0][1][j]) + (rex[0][2][j] + rex[0][3][j]);
            float zt = (rex[1][0][j] + rex[1][1][j]) + (rex[1][2][j] + rex[1][3][j]);
            float nt = (rex[2][0][j] + rex[2][1][j]) + (rex[2][2][j] + rex[2][3][j]);
            float r = 1.f/(1.f + __expf(-(ir + rt)));
            float z = 1.f/(1.f + __expf(-(izv + zt)));
            float x = inn + r*(nt + bh);
            float e2 = __expf(2.f*x);
            float n = 1.f - 2.f/(e2 + 1.f);          // tanh(x)
            float hn = (1.f - z)*n + z*hoj;
            y[((size_t)t*B_DIM + row)*H_DIM + j] = f2bf(hn);
            hoj = dn ? 0.f : hn;                     // dn=false on last chunk step
            ((_Float16*)hbuf[cur^1])[j] = (_Float16)hoj;
        }
        __syncthreads();
        cur ^= 1;
    }

    if(g == 0) h_carry[(size_t)row*H_DIM + j] = hoj;  // raw carry
}

// ---------------------------------------------------------------------------
// Actor head stage 2: logits[rows,32] = ah[rows,:256 of ld] @ W_a2 + b_a2 - (1-avail)*1e10
// ---------------------------------------------------------------------------
__global__ __launch_bounds__(256)
void actor2_kernel(const u16* __restrict__ ah, int ld, const float* __restrict__ W_a2,
                   const float* __restrict__ b_a2, const float* __restrict__ avail,
                   float* __restrict__ logits)
{
    __shared__ u16 ahs[64][264];
    const int tid = threadIdx.x;
    const int r0 = blockIdx.x*64;
    {
        int row = tid & 63;
        int c0 = (tid >> 6) * 64;
        const uint4* gp = (const uint4*)(ah + (size_t)(r0+row)*ld + c0);
        #pragma unroll
        for(int q=0;q<8;q++){
            uint4 u = gp[q];
            u32* dst = (u32*)&ahs[row][c0 + q*8];
            dst[0]=u.x; dst[1]=u.y; dst[2]=u.z; dst[3]=u.w;
        }
    }
    __syncthreads();
    const int c  = tid & 31;
    const int rg = tid >> 5;   // 0..7
    float acc[8]={0.f,0.f,0.f,0.f,0.f,0.f,0.f,0.f};
    float bc = b_a2[c];
    for(int k=0;k<H_DIM;k+=4){
        float w0 = W_a2[(k+0)*A_DIM + c];
        float w1 = W_a2[(k+1)*A_DIM + c];
        float w2 = W_a2[(k+2)*A_DIM + c];
        float w3 = W_a2[(k+3)*A_DIM + c];
        #pragma unroll
        for(int rr=0;rr<8;rr++){
            uint2 av = *(const uint2*)&ahs[rg*8+rr][k];
            float2 p0 = bfpair(av.x), p1 = bfpair(av.y);
            acc[rr] = fmaf(p0.x,w0,fmaf(p0.y,w1,fmaf(p1.x,w2,fmaf(p1.y,w3,acc[rr]))));
        }
    }
    #pragma unroll
    for(int rr=0;rr<8;rr++){
        int grow = r0 + rg*8 + rr;
        float av = avail[(size_t)grow*A_DIM + c];
        logits[(size_t)grow*A_DIM + c] = acc[rr] + bc - (1.f-av)*1e10f;
    }
}

// ---------------------------------------------------------------------------
// Critic head stage 2: value[row] = ch[row,:256 of ld] @ W_c2 + b_c2. Wave per row.
// ---------------------------------------------------------------------------
__global__ __launch_bounds__(256)
void critic2_kernel(const u16* __restrict__ ch, int ld, const float* __restrict__ W_c2,
                    const float* __restrict__ b_c2, float* __restrict__ value)
{
    const int lane = threadIdx.x & 63;
    const int wid  = threadIdx.x >> 6;
    const int row  = blockIdx.x*4 + wid;
    uint2 av = *(const uint2*)(ch + (size_t)row*ld + lane*4);
    float2 p0 = bfpair(av.x), p1 = bfpair(av.y);
    float4 wv = *(const float4*)(W_c2 + lane*4);
    float acc = p0.x*wv.x + p0.y*wv.y + p1.x*wv.z + p1.y*wv.w;
    #pragma unroll
    for(int off=32; off>0; off>>=1) acc += __shfl_down(acc, off, 64);
    if(lane==0) value[row] = acc + b_c2[0];
}

// ---------------------------------------------------------------------------
extern "C" void kernel_launch(void* const* d_in, const int* in_sizes, int n_in,
                              void* d_out, int out_size, void* d_ws, size_t ws_size,
                              hipStream_t stream)
{
    const float* hidden = (const float*)d_in[0];
    const float* obs    = (const float*)d_in[1];
    const void*  dones  = d_in[2];
    const float* avail  = (const float*)d_in[3];
    const float* W_emb  = (const float*)d_in[4];
    const float* b_emb  = (const float*)d_in[5];
    const float* Wi     = (const float*)d_in[6];
    const float* bi     = (const float*)d_in[7];
    const float* Whr    = (const float*)d_in[8];
    const float* Whz    = (const float*)d_in[9];
    const float* Whn    = (const float*)d_in[10];
    const float* bhn    = (const float*)d_in[11];
    const float* W_a1   = (const float*)d_in[12];
    const float* b_a1   = (const float*)d_in[13];
    const float* W_a2   = (const float*)d_in[14];
    const float* b_a2   = (const float*)d_in[15];
    const float* W_c1   = (const float*)d_in[16];
    const float* b_c1   = (const float*)d_in[17];
    const float* W_c2   = (const float*)d_in[18];
    const float* b_c2   = (const float*)d_in[19];

    float* out_hidden = (float*)d_out;                       // 65536
    float* out_logits = out_hidden + (size_t)B_DIM*H_DIM;    // 4194304
    float* out_value  = out_logits + (size_t)TB*A_DIM;       // 131072

    // ---- workspace layout (chunk size adapted to ws_size, deterministic) ----
    // fixed: wt_b + wiT + wacT(fused a1|c1) + wembT + h_carry + flags + b_ac
    const size_t fixed = 393216 + 393216 + 262144 + 65536 + 262144 + 256 + 2048;
    int Tc = 4;
    for(int cand = 64; cand >= 4; cand >>= 1){
        size_t need = fixed + (size_t)cand*(393216 /*gi*/ + 262144 /*emb|ac*/ + 131072 /*y*/);
        if(need <= ws_size){ Tc = cand; break; }
    }
    const int NC = T_DIM / Tc;

    uint8_t* ws = (uint8_t*)d_ws;
    size_t off = 0;
    u32*  wt_b    = (u32*)(ws + off); off += 393216;   // scan weights, packed f16
    u16*  wiT     = (u16*)(ws + off); off += 393216;   // Wi^T bf16 [768][256]
    u16*  wacT    = (u16*)(ws + off); off += 262144;   // [W_a1^T | W_c1^T] bf16 [512][256]
    u16*  wembT   = (u16*)(ws + off); off += 65536;    // W_emb^T bf16 [256][128]
    float* h_carry= (float*)(ws + off); off += 262144;
    int*  flags   = (int*)(ws + off); off += 256;
    float* b_ac   = (float*)(ws + off); off += 2048;   // b_a1|b_c1 (512 f32)
    u16*  gi_c    = (u16*)(ws + off); off += (size_t)Tc*393216;
    u16*  embac_c = (u16*)(ws + off); off += (size_t)Tc*262144;  // emb [Mc][256], later ac [Mc][512]
    u16*  y_c     = (u16*)(ws + off); off += (size_t)Tc*131072;
    u16*  emb_c   = embac_c;
    u16*  ac_c    = embac_c;

    zero_flags_kernel<<<1, 64, 0, stream>>>(flags);
    detect_kernel<<<64, 256, 0, stream>>>((const unsigned char*)dones, TB, flags);
    cvt_wt_kernel<<<384, 256, 0, stream>>>(Whr, Whz, Whn, wt_b);
    cvt_wT_kernel<<<768, 256, 0, stream>>>(Wi,   wiT,  256, 768);
    cvt_wT_kernel<<<256, 256, 0, stream>>>(W_a1, wacT,          256, 256);
    cvt_wT_kernel<<<256, 256, 0, stream>>>(W_c1, wacT + 65536,  256, 256);
    cvt_wT_kernel<<<128, 256, 0, stream>>>(W_emb, wembT, 128, 256);
    concat_bias_kernel<<<1, 256, 0, stream>>>(b_a1, b_c1, b_ac);
    hipMemcpyAsync(h_carry, hidden, (size_t)B_DIM*H_DIM*sizeof(float),
                   hipMemcpyDeviceToDevice, stream);

    const int Mc = Tc*B_DIM;
    const int gy = Mc/128;

    for(int c = 0; c < NC; ++c){
        const int t0 = c*Tc;
        const float* obs_c = obs + (size_t)t0*B_DIM*OBS_DIM;
        // emb = relu(obs @ W_emb + b_emb)  (MFMA, f32 A converted in staging)
        gemm_mfma_kernel<1,1><<<dim3(2,gy), 256, 0, stream>>>(obs_c, wembT, b_emb, emb_c, Mc, 256, 128);
        // gi = emb @ Wi + bi  (MFMA)
        gemm_mfma_kernel<0,0><<<dim3(6,gy), 256, 0, stream>>>(emb_c, wiT, bi, gi_c, Mc, 768, 256);
        // GRU scan chunk: 256 blocks (one per batch row) x 1024 threads
        scan_kernel<<<256, 1024, 0, stream>>>(gi_c, dones, flags, (const u32x4*)wt_b,
                                              bhn, h_carry, y_c, t0, Tc);
        // fused actor1|critic1 head: [Mc][512] = relu(y @ [W_a1|W_c1] + b_ac)
        gemm_mfma_kernel<1,0><<<dim3(4,gy), 256, 0, stream>>>(y_c, wacT, b_ac, ac_c, Mc, 512, 256);
        actor2_kernel<<<Mc/64, 256, 0, stream>>>(ac_c, 512, W_a2, b_a2,
                                                 avail + (size_t)t0*B_DIM*A_DIM,
                                                 out_logits + (size_t)t0*B_DIM*A_DIM);
        critic2_kernel<<<Mc/4, 256, 0, stream>>>(ac_c + 256, 512, W_c2, b_c2,
                                                 out_value + (size_t)t0*B_DIM);
    }

    hipMemcpyAsync(out_hidden, h_carry, (size_t)B_DIM*H_DIM*sizeof(float),
                   hipMemcpyDeviceToDevice, stream);
}

// Round 8
// 1162.901 us; speedup vs baseline: 1.6813x; 1.1566x over previous
//
#include <hip/hip_runtime.h>
#include <stdint.h>

#define T_DIM 512
#define B_DIM 256
#define OBS_DIM 128
#define H_DIM 256
#define A_DIM 32
#define TB (T_DIM*B_DIM)   // 131072

typedef unsigned short u16;
typedef unsigned int   u32;
typedef _Float16 half2v __attribute__((ext_vector_type(2)));
typedef __attribute__((ext_vector_type(8))) short short8;   // 8 bf16 (4 VGPRs)
typedef __attribute__((ext_vector_type(4))) float f32x4;
typedef __attribute__((ext_vector_type(4))) u32   u32x4;

__device__ __forceinline__ float bf2f(u16 v){ return __uint_as_float(((u32)v)<<16); }
__device__ __forceinline__ u16 f2bf(float f){
    u32 x = __float_as_uint(f);
    u32 r = x + 0x7fffu + ((x>>16)&1u);   // round-to-nearest-even
    return (u16)(r>>16);
}
__device__ __forceinline__ float2 bfpair(u32 u){
    return make_float2(__uint_as_float(u<<16), __uint_as_float(u & 0xffff0000u));
}

// packed-f16-pair dot: acc += a.lo*b.lo + a.hi*b.hi
__device__ __forceinline__ float dot2(u32 a, u32 b, float c){
#if __has_builtin(__builtin_amdgcn_fdot2)
    return __builtin_amdgcn_fdot2(__builtin_bit_cast(half2v,a),
                                  __builtin_bit_cast(half2v,b), c, false);
#else
    half2v ha = __builtin_bit_cast(half2v,a), hb = __builtin_bit_cast(half2v,b);
    return fmaf((float)ha[0],(float)hb[0], fmaf((float)ha[1],(float)hb[1], c));
#endif
}

// inline-asm dot2 (R7): measured identical to the intrinsic (the allocator's
// AGPR parking + per-use copy is unavoidable either way); kept as-is.
#define DOT2A(acc, w, h) \
    asm("v_dot2_f32_f16 %0, %1, %2, %0" : "+v"(acc) : "v"(w), "v"(h))

// ---------------------------------------------------------------------------
// dones dtype probe (u8 bool vs i32 vs f32) via nonzero byte positions mod 4.
// ---------------------------------------------------------------------------
__global__ void zero_flags_kernel(int* p){ if(threadIdx.x<4) p[threadIdx.x]=0; }

__global__ void detect_kernel(const unsigned char* __restrict__ d, int n, int* __restrict__ flags){
    int f=0;
    for(int p = blockIdx.x*blockDim.x+threadIdx.x; p<n; p += gridDim.x*blockDim.x){
        if(d[p]){ int m=p&3; if(m==1) f|=1; else if(m>=2) f|=2; }
    }
    if(f) atomicOr(flags, f);
}

// concat b_a1(256) | b_c1(256) -> b_ac(512) for the fused head-1 GEMM
__global__ void concat_bias_kernel(const float* __restrict__ a, const float* __restrict__ b,
                                   float* __restrict__ dst){
    int i = threadIdx.x;
    dst[i] = a[i];
    dst[256 + i] = b[i];
}

// ---------------------------------------------------------------------------
// Recurrent weights -> packed f16 pairs: dst[((m*32+q)*256 + j)*4 + e] packs
// k=2*(4q+e), 2*(4q+e)+1 of column j of matrix m (q covers k=8q..8q+7).
// ---------------------------------------------------------------------------
__global__ void cvt_wt_kernel(const float* __restrict__ Whr, const float* __restrict__ Whz,
                              const float* __restrict__ Whn, u32* __restrict__ dst){
    int i = blockIdx.x*blockDim.x + threadIdx.x;
    if(i >= 3*32*256*4) return;
    int e = i & 3;
    int j = (i >> 2) & 255;
    int q = (i >> 10) & 31;
    int m = i >> 15;
    const float* W = (m==0) ? Whr : (m==1) ? Whz : Whn;
    int kp = q*4 + e, k = 2*kp;
    _Float16 lo = (_Float16)W[(size_t)k    *H_DIM + j];
    _Float16 hi = (_Float16)W[(size_t)(k+1)*H_DIM + j];
    dst[i] = (u32)__builtin_bit_cast(u16,lo) | ((u32)__builtin_bit_cast(u16,hi) << 16);
}

// GEMM weight f32 [K][N] -> bf16 transposed [N][K]
__global__ void cvt_wT_kernel(const float* __restrict__ W, u16* __restrict__ dst,
                              int K, int N){
    int i = blockIdx.x*blockDim.x + threadIdx.x;
    if(i >= K*N) return;
    int n = i / K;
    int k = i - n*K;
    dst[i] = f2bf(W[(size_t)k*N + n]);
}

// ---------------------------------------------------------------------------
// MFMA bf16 GEMM: C[M,N](bf16) = opt_relu(A @ Bt^T + bias), Bt bf16 [N][K].
// A is bf16 (AF32=0) or f32 converted during staging (AF32=1).
// 128x128 tile, BK=32, 4 waves 2x2, 16x mfma_f32_16x16x32_bf16 each.
// ---------------------------------------------------------------------------
template<int RELU, int AF32>
__global__ __launch_bounds__(256, 2)
void gemm_mfma_kernel(const void* __restrict__ A_, const u16* __restrict__ Bt,
                      const float* __restrict__ bias, u16* __restrict__ C,
                      int M, int N, int K)
{
    __shared__ u16 As[128*32];
    __shared__ u16 Bs[128*32];
    const int tid  = threadIdx.x;
    const int wave = tid >> 6;
    const int lane = tid & 63;
    const int ln15 = lane & 15;
    const int quad = lane >> 4;
    const int wm = wave & 1, wn = wave >> 1;
    const int rowBase = blockIdx.y*128;
    const int colBase = blockIdx.x*128;

    f32x4 acc[4][4] = {};

    const int sr = tid >> 1;
    const int sc = (tid & 1) * 16;

    for(int kb = 0; kb < K; kb += 32){
        if(AF32){
            const float* af = (const float*)A_;
            const float* ag = af + (size_t)(rowBase+sr)*K + kb + sc;
            float4 f0 = *(const float4*)ag;
            float4 f1 = *(const float4*)(ag+4);
            float4 f2 = *(const float4*)(ag+8);
            float4 f3 = *(const float4*)(ag+12);
            u16 tmp[16] = { f2bf(f0.x),f2bf(f0.y),f2bf(f0.z),f2bf(f0.w),
                            f2bf(f1.x),f2bf(f1.y),f2bf(f1.z),f2bf(f1.w),
                            f2bf(f2.x),f2bf(f2.y),f2bf(f2.z),f2bf(f2.w),
                            f2bf(f3.x),f2bf(f3.y),f2bf(f3.z),f2bf(f3.w) };
            *(uint4*)&As[sr*32 + sc]     = *(const uint4*)&tmp[0];
            *(uint4*)&As[sr*32 + sc + 8] = *(const uint4*)&tmp[8];
        } else {
            const u16* ab = (const u16*)A_;
            const u16* ag = ab + (size_t)(rowBase+sr)*K + kb + sc;
            uint4 av0 = *(const uint4*)ag;
            uint4 av1 = *(const uint4*)(ag+8);
            *(uint4*)&As[sr*32 + sc]     = av0;
            *(uint4*)&As[sr*32 + sc + 8] = av1;
        }
        {
            const u16* bg = Bt + (size_t)(colBase+sr)*K + kb + sc;
            uint4 bv0 = *(const uint4*)bg;
            uint4 bv1 = *(const uint4*)(bg+8);
            *(uint4*)&Bs[sr*32 + sc]     = bv0;
            *(uint4*)&Bs[sr*32 + sc + 8] = bv1;
        }
        __syncthreads();

        short8 af[4], bf[4];
        #pragma unroll
        for(int mt=0;mt<4;mt++)
            af[mt] = *(const short8*)&As[(wm*64+mt*16+ln15)*32 + quad*8];
        #pragma unroll
        for(int nt=0;nt<4;nt++)
            bf[nt] = *(const short8*)&Bs[(wn*64+nt*16+ln15)*32 + quad*8];
        #pragma unroll
        for(int mt=0;mt<4;mt++){
            #pragma unroll
            for(int nt=0;nt<4;nt++){
                acc[mt][nt] = __builtin_amdgcn_mfma_f32_16x16x32_bf16(
                                  af[mt], bf[nt], acc[mt][nt], 0, 0, 0);
            }
        }
        __syncthreads();
    }

    #pragma unroll
    for(int nt=0;nt<4;nt++){
        int n = colBase + wn*64 + nt*16 + ln15;
        float bv = bias[n];
        #pragma unroll
        for(int mt=0;mt<4;mt++){
            #pragma unroll
            for(int r=0;r<4;r++){
                int m = rowBase + wm*64 + mt*16 + quad*4 + r;
                float v = acc[mt][nt][r] + bv;
                if(RELU) v = fmaxf(v, 0.f);
                C[(size_t)m*N + n] = f2bf(v);
            }
        }
    }
}

// ---------------------------------------------------------------------------
// GRU scan (R2/R7 structure -- settled local optimum for the dot phase).
// 256 blocks (one batch row) x 1024 threads; thread (g=k-quarter, j=column)
// owns k-range [64g,64g+64) of column j, all 3 matrices (96 packed-f16 u32;
// the allocator parks these in AGPRs and pays one v_accvgpr_read per use --
// R2/R3/R5/R7 proved this unavoidable; tax accepted).
// R8 trims: (a) g0 keeps its own partials in registers -- rex written by
// g!=0 only (9 ds_writes saved per SIMD) and gate phase reads 9 not 12;
// (b) hbuf write issues before the y store so its lgkm drains before
// barrier2. Chunk size now adapts up to Tc=512 (see kernel_launch): one
// dispatch amortizes the per-dispatch weight reload (24 global loads/thread)
// across all 512 steps instead of 8x.
// ---------------------------------------------------------------------------
__global__ __attribute__((amdgpu_flat_work_group_size(1024,1024), amdgpu_waves_per_eu(4,4)))
void scan_kernel(const u16* __restrict__ gi, const void* __restrict__ dones,
                 const int* __restrict__ flags, const u32x4* __restrict__ Wt4,
                 const float* __restrict__ bhn, float* __restrict__ h_carry,
                 u16* __restrict__ y, int t0, int Tc)
{
    __shared__ __align__(16) u32 hbuf[2][128];   // 256 packed f16 each
    __shared__ float rex[3][4][256];             // partial dots (g=1..3 used)
    const int tid = threadIdx.x;
    const int j   = tid & 255;
    const int g   = tid >> 8;      // k-quarter 0..3
    const int row = blockIdx.x;
    const int fl  = flags[0];
    const int mode = (fl&1) ? 0 : ((fl&2) ? 2 : 1);  // 0=u8, 1=i32, 2=f32

    auto getdone = [&](int t)->bool{
        int idx = t*B_DIM + row;
        if(mode==0) return ((const unsigned char*)dones)[idx] != 0;
        if(mode==1) return ((const int*)dones)[idx] != 0;
        return ((const float*)dones)[idx] != 0.f;
    };

    // ---- one-time weight load: k-quarter g of column j, all three mats ----
    const u32x4* baseR = Wt4 + (size_t)( 0 + g*8)*256 + j;
    const u32x4* baseZ = Wt4 + (size_t)(32 + g*8)*256 + j;
    const u32x4* baseN = Wt4 + (size_t)(64 + g*8)*256 + j;
    u32 wr[32], wz[32], wn[32];
    #pragma unroll
    for(int q=0;q<8;q++){
        u32x4 tr = baseR[(size_t)q*256]; wr[4*q]=tr[0]; wr[4*q+1]=tr[1]; wr[4*q+2]=tr[2]; wr[4*q+3]=tr[3];
        u32x4 tz = baseZ[(size_t)q*256]; wz[4*q]=tz[0]; wz[4*q+1]=tz[1]; wz[4*q+2]=tz[2]; wz[4*q+3]=tz[3];
        u32x4 tn = baseN[(size_t)q*256]; wn[4*q]=tn[0]; wn[4*q+1]=tn[1]; wn[4*q+2]=tn[2]; wn[4*q+3]=tn[3];
    }

    const float bh = bhn[j];
    float hoj = 0.f;
    if(g == 0){
        bool d0 = getdone(t0);
        hoj = d0 ? 0.f : h_carry[(size_t)row*H_DIM + j];
        ((_Float16*)hbuf[0])[j] = (_Float16)hoj;
    }
    __syncthreads();

    int cur = 0;
    for(int t=0; t<Tc; ++t){
        // gate-input loads up front (latency hides under the dot phase)
        size_t gbase = ((size_t)t*B_DIM + row)*768;
        float ir=0.f, izv=0.f, inn=0.f; bool dn=false;
        if(g == 0){
            ir  = bf2f(gi[gbase + j]);
            izv = bf2f(gi[gbase + 256 + j]);
            inn = bf2f(gi[gbase + 512 + j]);
            dn  = (t < Tc-1) ? getdone(t0+t+1) : false;
        }

        // partial dots over this thread's k-quarter, all three matrices.
        // hv is a wave-uniform broadcast read, reused across r/z/n.
        float r0=0.f,r1=0.f,z0=0.f,z1=0.f,n0=0.f,n1=0.f;
        const u32x4* hb = (const u32x4*)hbuf[cur] + g*8;
        #pragma unroll
        for(int q=0;q<8;q++){
            u32x4 hv = hb[q];
            DOT2A(r0, wr[4*q  ], hv[0]); DOT2A(r1, wr[4*q+1], hv[1]);
            DOT2A(r0, wr[4*q+2], hv[2]); DOT2A(r1, wr[4*q+3], hv[3]);
            DOT2A(z0, wz[4*q  ], hv[0]); DOT2A(z1, wz[4*q+1], hv[1]);
            DOT2A(z0, wz[4*q+2], hv[2]); DOT2A(z1, wz[4*q+3], hv[3]);
            DOT2A(n0, wn[4*q  ], hv[0]); DOT2A(n1, wn[4*q+1], hv[1]);
            DOT2A(n0, wn[4*q+2], hv[2]); DOT2A(n1, wn[4*q+3], hv[3]);
        }
        if(g != 0){
            rex[0][g][j] = r0 + r1;
            rex[1][g][j] = z0 + z1;
            rex[2][g][j] = n0 + n1;
        }
        __syncthreads();

        if(g == 0){
            float rt = (r0 + r1) + rex[0][1][j] + (rex[0][2][j] + rex[0][3][j]);
            float zt = (z0 + z1) + rex[1][1][j] + (rex[1][2][j] + rex[1][3][j]);
            float nt = (n0 + n1) + rex[2][1][j] + (rex[2][2][j] + rex[2][3][j]);
            float r = 1.f/(1.f + __expf(-(ir + rt)));
            float z = 1.f/(1.f + __expf(-(izv + zt)));
            float x = inn + r*(nt + bh);
            float e2 = __expf(2.f*x);
            float n = 1.f - 2.f/(e2 + 1.f);          // tanh(x)
            float hn = (1.f - z)*n + z*hoj;
            hoj = dn ? 0.f : hn;                     // dn=false on last chunk step
            ((_Float16*)hbuf[cur^1])[j] = (_Float16)hoj;   // issue before y store
            y[((size_t)t*B_DIM + row)*H_DIM + j] = f2bf(hn);
        }
        __syncthreads();
        cur ^= 1;
    }

    if(g == 0) h_carry[(size_t)row*H_DIM + j] = hoj;  // raw carry
}

// ---------------------------------------------------------------------------
// Actor head stage 2: logits[rows,32] = ah[rows,:256 of ld] @ W_a2 + b_a2 - (1-avail)*1e10
// ---------------------------------------------------------------------------
__global__ __launch_bounds__(256)
void actor2_kernel(const u16* __restrict__ ah, int ld, const float* __restrict__ W_a2,
                   const float* __restrict__ b_a2, const float* __restrict__ avail,
                   float* __restrict__ logits)
{
    __shared__ u16 ahs[64][264];
    const int tid = threadIdx.x;
    const int r0 = blockIdx.x*64;
    {
        int row = tid & 63;
        int c0 = (tid >> 6) * 64;
        const uint4* gp = (const uint4*)(ah + (size_t)(r0+row)*ld + c0);
        #pragma unroll
        for(int q=0;q<8;q++){
            uint4 u = gp[q];
            u32* dst = (u32*)&ahs[row][c0 + q*8];
            dst[0]=u.x; dst[1]=u.y; dst[2]=u.z; dst[3]=u.w;
        }
    }
    __syncthreads();
    const int c  = tid & 31;
    const int rg = tid >> 5;   // 0..7
    float acc[8]={0.f,0.f,0.f,0.f,0.f,0.f,0.f,0.f};
    float bc = b_a2[c];
    for(int k=0;k<H_DIM;k+=4){
        float w0 = W_a2[(k+0)*A_DIM + c];
        float w1 = W_a2[(k+1)*A_DIM + c];
        float w2 = W_a2[(k+2)*A_DIM + c];
        float w3 = W_a2[(k+3)*A_DIM + c];
        #pragma unroll
        for(int rr=0;rr<8;rr++){
            uint2 av = *(const uint2*)&ahs[rg*8+rr][k];
            float2 p0 = bfpair(av.x), p1 = bfpair(av.y);
            acc[rr] = fmaf(p0.x,w0,fmaf(p0.y,w1,fmaf(p1.x,w2,fmaf(p1.y,w3,acc[rr]))));
        }
    }
    #pragma unroll
    for(int rr=0;rr<8;rr++){
        int grow = r0 + rg*8 + rr;
        float av = avail[(size_t)grow*A_DIM + c];
        logits[(size_t)grow*A_DIM + c] = acc[rr] + bc - (1.f-av)*1e10f;
    }
}

// ---------------------------------------------------------------------------
// Critic head stage 2: value[row] = ch[row,:256 of ld] @ W_c2 + b_c2. Wave per row.
// ---------------------------------------------------------------------------
__global__ __launch_bounds__(256)
void critic2_kernel(const u16* __restrict__ ch, int ld, const float* __restrict__ W_c2,
                    const float* __restrict__ b_c2, float* __restrict__ value)
{
    const int lane = threadIdx.x & 63;
    const int wid  = threadIdx.x >> 6;
    const int row  = blockIdx.x*4 + wid;
    uint2 av = *(const uint2*)(ch + (size_t)row*ld + lane*4);
    float2 p0 = bfpair(av.x), p1 = bfpair(av.y);
    float4 wv = *(const float4*)(W_c2 + lane*4);
    float acc = p0.x*wv.x + p0.y*wv.y + p1.x*wv.z + p1.y*wv.w;
    #pragma unroll
    for(int off=32; off>0; off>>=1) acc += __shfl_down(acc, off, 64);
    if(lane==0) value[row] = acc + b_c2[0];
}

// ---------------------------------------------------------------------------
extern "C" void kernel_launch(void* const* d_in, const int* in_sizes, int n_in,
                              void* d_out, int out_size, void* d_ws, size_t ws_size,
                              hipStream_t stream)
{
    const float* hidden = (const float*)d_in[0];
    const float* obs    = (const float*)d_in[1];
    const void*  dones  = d_in[2];
    const float* avail  = (const float*)d_in[3];
    const float* W_emb  = (const float*)d_in[4];
    const float* b_emb  = (const float*)d_in[5];
    const float* Wi     = (const float*)d_in[6];
    const float* bi     = (const float*)d_in[7];
    const float* Whr    = (const float*)d_in[8];
    const float* Whz    = (const float*)d_in[9];
    const float* Whn    = (const float*)d_in[10];
    const float* bhn    = (const float*)d_in[11];
    const float* W_a1   = (const float*)d_in[12];
    const float* b_a1   = (const float*)d_in[13];
    const float* W_a2   = (const float*)d_in[14];
    const float* b_a2   = (const float*)d_in[15];
    const float* W_c1   = (const float*)d_in[16];
    const float* b_c1   = (const float*)d_in[17];
    const float* W_c2   = (const float*)d_in[18];
    const float* b_c2   = (const float*)d_in[19];

    float* out_hidden = (float*)d_out;                       // 65536
    float* out_logits = out_hidden + (size_t)B_DIM*H_DIM;    // 4194304
    float* out_value  = out_logits + (size_t)TB*A_DIM;       // 131072

    // ---- workspace layout (chunk size adapted to ws_size, deterministic) ----
    // fixed: wt_b + wiT + wacT(fused a1|c1) + wembT + h_carry + flags + b_ac
    // R8: cand range extended to 512 -- a single chunk runs all GEMMs at
    // M=131072 and ONE scan dispatch (weight reload amortized 8x). Falls
    // back to smaller Tc automatically when ws_size doesn't permit.
    const size_t fixed = 393216 + 393216 + 262144 + 65536 + 262144 + 256 + 2048;
    int Tc = 4;
    for(int cand = 512; cand >= 4; cand >>= 1){
        size_t need = fixed + (size_t)cand*(393216 /*gi*/ + 262144 /*emb|ac*/ + 131072 /*y*/);
        if(need <= ws_size){ Tc = cand; break; }
    }
    const int NC = T_DIM / Tc;

    uint8_t* ws = (uint8_t*)d_ws;
    size_t off = 0;
    u32*  wt_b    = (u32*)(ws + off); off += 393216;   // scan weights, packed f16
    u16*  wiT     = (u16*)(ws + off); off += 393216;   // Wi^T bf16 [768][256]
    u16*  wacT    = (u16*)(ws + off); off += 262144;   // [W_a1^T | W_c1^T] bf16 [512][256]
    u16*  wembT   = (u16*)(ws + off); off += 65536;    // W_emb^T bf16 [256][128]
    float* h_carry= (float*)(ws + off); off += 262144;
    int*  flags   = (int*)(ws + off); off += 256;
    float* b_ac   = (float*)(ws + off); off += 2048;   // b_a1|b_c1 (512 f32)
    u16*  gi_c    = (u16*)(ws + off); off += (size_t)Tc*393216;
    u16*  embac_c = (u16*)(ws + off); off += (size_t)Tc*262144;  // emb [Mc][256], later ac [Mc][512]
    u16*  y_c     = (u16*)(ws + off); off += (size_t)Tc*131072;
    u16*  emb_c   = embac_c;
    u16*  ac_c    = embac_c;

    zero_flags_kernel<<<1, 64, 0, stream>>>(flags);
    detect_kernel<<<64, 256, 0, stream>>>((const unsigned char*)dones, TB, flags);
    cvt_wt_kernel<<<384, 256, 0, stream>>>(Whr, Whz, Whn, wt_b);
    cvt_wT_kernel<<<768, 256, 0, stream>>>(Wi,   wiT,  256, 768);
    cvt_wT_kernel<<<256, 256, 0, stream>>>(W_a1, wacT,          256, 256);
    cvt_wT_kernel<<<256, 256, 0, stream>>>(W_c1, wacT + 65536,  256, 256);
    cvt_wT_kernel<<<128, 256, 0, stream>>>(W_emb, wembT, 128, 256);
    concat_bias_kernel<<<1, 256, 0, stream>>>(b_a1, b_c1, b_ac);
    hipMemcpyAsync(h_carry, hidden, (size_t)B_DIM*H_DIM*sizeof(float),
                   hipMemcpyDeviceToDevice, stream);

    const int Mc = Tc*B_DIM;
    const int gy = Mc/128;

    for(int c = 0; c < NC; ++c){
        const int t0 = c*Tc;
        const float* obs_c = obs + (size_t)t0*B_DIM*OBS_DIM;
        // emb = relu(obs @ W_emb + b_emb)  (MFMA, f32 A converted in staging)
        gemm_mfma_kernel<1,1><<<dim3(2,gy), 256, 0, stream>>>(obs_c, wembT, b_emb, emb_c, Mc, 256, 128);
        // gi = emb @ Wi + bi  (MFMA)
        gemm_mfma_kernel<0,0><<<dim3(6,gy), 256, 0, stream>>>(emb_c, wiT, bi, gi_c, Mc, 768, 256);
        // GRU scan chunk: 256 blocks (one per batch row) x 1024 threads
        scan_kernel<<<256, 1024, 0, stream>>>(gi_c, dones, flags, (const u32x4*)wt_b,
                                              bhn, h_carry, y_c, t0, Tc);
        // fused actor1|critic1 head: [Mc][512] = relu(y @ [W_a1|W_c1] + b_ac)
        gemm_mfma_kernel<1,0><<<dim3(4,gy), 256, 0, stream>>>(y_c, wacT, b_ac, ac_c, Mc, 512, 256);
        actor2_kernel<<<Mc/64, 256, 0, stream>>>(ac_c, 512, W_a2, b_a2,
                                                 avail + (size_t)t0*B_DIM*A_DIM,
                                                 out_logits + (size_t)t0*B_DIM*A_DIM);
        critic2_kernel<<<Mc/4, 256, 0, stream>>>(ac_c + 256, 512, W_c2, b_c2,
                                                 out_value + (size_t)t0*B_DIM);
    }

    hipMemcpyAsync(out_hidden, h_carry, (size_t)B_DIM*H_DIM*sizeof(float),
                   hipMemcpyDeviceToDevice, stream);
}

// Round 9
// 1125.274 us; speedup vs baseline: 1.7375x; 1.0334x over previous
//
#include <hip/hip_runtime.h>
#include <stdint.h>

#define T_DIM 512
#define B_DIM 256
#define OBS_DIM 128
#define H_DIM 256
#define A_DIM 32
#define TB (T_DIM*B_DIM)   // 131072

typedef unsigned short u16;
typedef unsigned int   u32;
typedef _Float16 half2v __attribute__((ext_vector_type(2)));
typedef __attribute__((ext_vector_type(8))) short short8;   // 8 bf16 (4 VGPRs)
typedef __attribute__((ext_vector_type(4))) float f32x4;
typedef __attribute__((ext_vector_type(4))) u32   u32x4;

__device__ __forceinline__ float bf2f(u16 v){ return __uint_as_float(((u32)v)<<16); }
__device__ __forceinline__ u16 f2bf(float f){
    u32 x = __float_as_uint(f);
    u32 r = x + 0x7fffu + ((x>>16)&1u);   // round-to-nearest-even
    return (u16)(r>>16);
}
__device__ __forceinline__ float2 bfpair(u32 u){
    return make_float2(__uint_as_float(u<<16), __uint_as_float(u & 0xffff0000u));
}

// packed-f16-pair dot: acc += a.lo*b.lo + a.hi*b.hi
__device__ __forceinline__ float dot2(u32 a, u32 b, float c){
#if __has_builtin(__builtin_amdgcn_fdot2)
    return __builtin_amdgcn_fdot2(__builtin_bit_cast(half2v,a),
                                  __builtin_bit_cast(half2v,b), c, false);
#else
    half2v ha = __builtin_bit_cast(half2v,a), hb = __builtin_bit_cast(half2v,b);
    return fmaf((float)ha[0],(float)hb[0], fmaf((float)ha[1],(float)hb[1], c));
#endif
}

// inline-asm dot2 (R7): measured identical to the intrinsic (the allocator's
// AGPR parking + per-use copy is unavoidable either way); kept as-is.
#define DOT2A(acc, w, h) \
    asm("v_dot2_f32_f16 %0, %1, %2, %0" : "+v"(acc) : "v"(w), "v"(h))

// async global->LDS 16B copy: LDS dest is wave-uniform base + lane*16,
// global src is per-lane (m97 ladder step: +69% on this GEMM structure).
#define GLOAD16(gsrc, ldst) \
    __builtin_amdgcn_global_load_lds( \
        (const __attribute__((address_space(1))) void*)(gsrc), \
        (__attribute__((address_space(3))) void*)(ldst), 16, 0, 0)

// ---------------------------------------------------------------------------
// dones dtype probe (u8 bool vs i32 vs f32) via nonzero byte positions mod 4.
// ---------------------------------------------------------------------------
__global__ void zero_flags_kernel(int* p){ if(threadIdx.x<4) p[threadIdx.x]=0; }

__global__ void detect_kernel(const unsigned char* __restrict__ d, int n, int* __restrict__ flags){
    int f=0;
    for(int p = blockIdx.x*blockDim.x+threadIdx.x; p<n; p += gridDim.x*blockDim.x){
        if(d[p]){ int m=p&3; if(m==1) f|=1; else if(m>=2) f|=2; }
    }
    if(f) atomicOr(flags, f);
}

// concat b_a1(256) | b_c1(256) -> b_ac(512) for the fused head-1 GEMM
__global__ void concat_bias_kernel(const float* __restrict__ a, const float* __restrict__ b,
                                   float* __restrict__ dst){
    int i = threadIdx.x;
    dst[i] = a[i];
    dst[256 + i] = b[i];
}

// ---------------------------------------------------------------------------
// Recurrent weights -> packed f16 pairs: dst[((m*32+q)*256 + j)*4 + e] packs
// k=2*(4q+e), 2*(4q+e)+1 of column j of matrix m (q covers k=8q..8q+7).
// ---------------------------------------------------------------------------
__global__ void cvt_wt_kernel(const float* __restrict__ Whr, const float* __restrict__ Whz,
                              const float* __restrict__ Whn, u32* __restrict__ dst){
    int i = blockIdx.x*blockDim.x + threadIdx.x;
    if(i >= 3*32*256*4) return;
    int e = i & 3;
    int j = (i >> 2) & 255;
    int q = (i >> 10) & 31;
    int m = i >> 15;
    const float* W = (m==0) ? Whr : (m==1) ? Whz : Whn;
    int kp = q*4 + e, k = 2*kp;
    _Float16 lo = (_Float16)W[(size_t)k    *H_DIM + j];
    _Float16 hi = (_Float16)W[(size_t)(k+1)*H_DIM + j];
    dst[i] = (u32)__builtin_bit_cast(u16,lo) | ((u32)__builtin_bit_cast(u16,hi) << 16);
}

// GEMM weight f32 [K][N] -> bf16 transposed [N][K]
__global__ void cvt_wT_kernel(const float* __restrict__ W, u16* __restrict__ dst,
                              int K, int N){
    int i = blockIdx.x*blockDim.x + threadIdx.x;
    if(i >= K*N) return;
    int n = i / K;
    int k = i - n*K;
    dst[i] = f2bf(W[(size_t)k*N + n]);
}

// ---------------------------------------------------------------------------
// MFMA bf16 GEMM: C[M,N](bf16) = opt_relu(A @ Bt^T + bias), Bt bf16 [N][K].
// A is bf16 (AF32=0) or f32 converted during staging (AF32=1).
// 128x128 tile, BK=32, 4 waves 2x2, 16x mfma_f32_16x16x32_bf16 each.
// R9: bf16 staging via global_load_lds width=16 (4 calls/thread/K-iter):
// thread tid covers tile bytes tid*16 and 4096+tid*16 -> row tid>>2,
// col (tid&3)*8 u16; LDS dest wave-uniform base wave*1024 (+4096).
// ---------------------------------------------------------------------------
template<int RELU, int AF32>
__global__ __launch_bounds__(256, 2)
void gemm_mfma_kernel(const void* __restrict__ A_, const u16* __restrict__ Bt,
                      const float* __restrict__ bias, u16* __restrict__ C,
                      int M, int N, int K)
{
    __shared__ u16 As[128*32];
    __shared__ u16 Bs[128*32];
    const int tid  = threadIdx.x;
    const int wave = tid >> 6;
    const int lane = tid & 63;
    const int ln15 = lane & 15;
    const int quad = lane >> 4;
    const int wm = wave & 1, wn = wave >> 1;
    const int rowBase = blockIdx.y*128;
    const int colBase = blockIdx.x*128;

    f32x4 acc[4][4] = {};

    // async-staging decomposition (bf16 tiles)
    const int rA   = tid >> 2;          // row within 64-row chunk
    const int cA   = (tid & 3) * 8;     // col offset in u16
    u16* AsW0 = As + wave*512;          // chunk0 LDS base (bytes wave*1024)
    u16* AsW1 = As + 2048 + wave*512;   // chunk1 (+4096 B)
    u16* BsW0 = Bs + wave*512;
    u16* BsW1 = Bs + 2048 + wave*512;

    // AF32 fallback staging coords
    const int sr = tid >> 1;
    const int sc = (tid & 1) * 16;

    for(int kb = 0; kb < K; kb += 32){
        if(AF32){
            const float* af = (const float*)A_;
            const float* ag = af + (size_t)(rowBase+sr)*K + kb + sc;
            float4 f0 = *(const float4*)ag;
            float4 f1 = *(const float4*)(ag+4);
            float4 f2 = *(const float4*)(ag+8);
            float4 f3 = *(const float4*)(ag+12);
            u16 tmp[16] = { f2bf(f0.x),f2bf(f0.y),f2bf(f0.z),f2bf(f0.w),
                            f2bf(f1.x),f2bf(f1.y),f2bf(f1.z),f2bf(f1.w),
                            f2bf(f2.x),f2bf(f2.y),f2bf(f2.z),f2bf(f2.w),
                            f2bf(f3.x),f2bf(f3.y),f2bf(f3.z),f2bf(f3.w) };
            *(uint4*)&As[sr*32 + sc]     = *(const uint4*)&tmp[0];
            *(uint4*)&As[sr*32 + sc + 8] = *(const uint4*)&tmp[8];
        } else {
            const u16* ab = (const u16*)A_;
            GLOAD16(ab + (size_t)(rowBase +      rA)*K + kb + cA, AsW0);
            GLOAD16(ab + (size_t)(rowBase + 64 + rA)*K + kb + cA, AsW1);
        }
        GLOAD16(Bt + (size_t)(colBase +      rA)*K + kb + cA, BsW0);
        GLOAD16(Bt + (size_t)(colBase + 64 + rA)*K + kb + cA, BsW1);
        __syncthreads();

        short8 af[4], bf[4];
        #pragma unroll
        for(int mt=0;mt<4;mt++)
            af[mt] = *(const short8*)&As[(wm*64+mt*16+ln15)*32 + quad*8];
        #pragma unroll
        for(int nt=0;nt<4;nt++)
            bf[nt] = *(const short8*)&Bs[(wn*64+nt*16+ln15)*32 + quad*8];
        #pragma unroll
        for(int mt=0;mt<4;mt++){
            #pragma unroll
            for(int nt=0;nt<4;nt++){
                acc[mt][nt] = __builtin_amdgcn_mfma_f32_16x16x32_bf16(
                                  af[mt], bf[nt], acc[mt][nt], 0, 0, 0);
            }
        }
        __syncthreads();
    }

    #pragma unroll
    for(int nt=0;nt<4;nt++){
        int n = colBase + wn*64 + nt*16 + ln15;
        float bv = bias[n];
        #pragma unroll
        for(int mt=0;mt<4;mt++){
            #pragma unroll
            for(int r=0;r<4;r++){
                int m = rowBase + wm*64 + mt*16 + quad*4 + r;
                float v = acc[mt][nt][r] + bv;
                if(RELU) v = fmaxf(v, 0.f);
                C[(size_t)m*N + n] = f2bf(v);
            }
        }
    }
}

// ---------------------------------------------------------------------------
// GRU scan (R2/R7/R8 structure -- settled). 256 blocks x 1024 threads;
// thread (g=k-quarter, j=column) owns k-range [64g,64g+64) of column j for
// all 3 matrices (96 packed-f16 u32; allocator AGPR-parks them, tax accepted
// -- R2/R3/R5/R7). At Tc=512 the per-dispatch weight reload is amortized
// once over all steps (R8: 0.725us/step vs 1.48 at Tc=64).
// ---------------------------------------------------------------------------
__global__ __attribute__((amdgpu_flat_work_group_size(1024,1024), amdgpu_waves_per_eu(4,4)))
void scan_kernel(const u16* __restrict__ gi, const void* __restrict__ dones,
                 const int* __restrict__ flags, const u32x4* __restrict__ Wt4,
                 const float* __restrict__ bhn, float* __restrict__ h_carry,
                 u16* __restrict__ y, int t0, int Tc)
{
    __shared__ __align__(16) u32 hbuf[2][128];   // 256 packed f16 each
    __shared__ float rex[3][4][256];             // partial dots (g=1..3 used)
    const int tid = threadIdx.x;
    const int j   = tid & 255;
    const int g   = tid >> 8;      // k-quarter 0..3
    const int row = blockIdx.x;
    const int fl  = flags[0];
    const int mode = (fl&1) ? 0 : ((fl&2) ? 2 : 1);  // 0=u8, 1=i32, 2=f32

    auto getdone = [&](int t)->bool{
        int idx = t*B_DIM + row;
        if(mode==0) return ((const unsigned char*)dones)[idx] != 0;
        if(mode==1) return ((const int*)dones)[idx] != 0;
        return ((const float*)dones)[idx] != 0.f;
    };

    // ---- one-time weight load: k-quarter g of column j, all three mats ----
    const u32x4* baseR = Wt4 + (size_t)( 0 + g*8)*256 + j;
    const u32x4* baseZ = Wt4 + (size_t)(32 + g*8)*256 + j;
    const u32x4* baseN = Wt4 + (size_t)(64 + g*8)*256 + j;
    u32 wr[32], wz[32], wn[32];
    #pragma unroll
    for(int q=0;q<8;q++){
        u32x4 tr = baseR[(size_t)q*256]; wr[4*q]=tr[0]; wr[4*q+1]=tr[1]; wr[4*q+2]=tr[2]; wr[4*q+3]=tr[3];
        u32x4 tz = baseZ[(size_t)q*256]; wz[4*q]=tz[0]; wz[4*q+1]=tz[1]; wz[4*q+2]=tz[2]; wz[4*q+3]=tz[3];
        u32x4 tn = baseN[(size_t)q*256]; wn[4*q]=tn[0]; wn[4*q+1]=tn[1]; wn[4*q+2]=tn[2]; wn[4*q+3]=tn[3];
    }

    const float bh = bhn[j];
    float hoj = 0.f;
    if(g == 0){
        bool d0 = getdone(t0);
        hoj = d0 ? 0.f : h_carry[(size_t)row*H_DIM + j];
        ((_Float16*)hbuf[0])[j] = (_Float16)hoj;
    }
    __syncthreads();

    int cur = 0;
    for(int t=0; t<Tc; ++t){
        // gate-input loads up front (latency hides under the dot phase)
        size_t gbase = ((size_t)t*B_DIM + row)*768;
        float ir=0.f, izv=0.f, inn=0.f; bool dn=false;
        if(g == 0){
            ir  = bf2f(gi[gbase + j]);
            izv = bf2f(gi[gbase + 256 + j]);
            inn = bf2f(gi[gbase + 512 + j]);
            dn  = (t < Tc-1) ? getdone(t0+t+1) : false;
        }

        // partial dots over this thread's k-quarter, all three matrices.
        // hv is a wave-uniform broadcast read, reused across r/z/n.
        float r0=0.f,r1=0.f,z0=0.f,z1=0.f,n0=0.f,n1=0.f;
        const u32x4* hb = (const u32x4*)hbuf[cur] + g*8;
        #pragma unroll
        for(int q=0;q<8;q++){
            u32x4 hv = hb[q];
            DOT2A(r0, wr[4*q  ], hv[0]); DOT2A(r1, wr[4*q+1], hv[1]);
            DOT2A(r0, wr[4*q+2], hv[2]); DOT2A(r1, wr[4*q+3], hv[3]);
            DOT2A(z0, wz[4*q  ], hv[0]); DOT2A(z1, wz[4*q+1], hv[1]);
            DOT2A(z0, wz[4*q+2], hv[2]); DOT2A(z1, wz[4*q+3], hv[3]);
            DOT2A(n0, wn[4*q  ], hv[0]); DOT2A(n1, wn[4*q+1], hv[1]);
            DOT2A(n0, wn[4*q+2], hv[2]); DOT2A(n1, wn[4*q+3], hv[3]);
        }
        if(g != 0){
            rex[0][g][j] = r0 + r1;
            rex[1][g][j] = z0 + z1;
            rex[2][g][j] = n0 + n1;
        }
        __syncthreads();

        if(g == 0){
            float rt = (r0 + r1) + rex[0][1][j] + (rex[0][2][j] + rex[0][3][j]);
            float zt = (z0 + z1) + rex[1][1][j] + (rex[1][2][j] + rex[1][3][j]);
            float nt = (n0 + n1) + rex[2][1][j] + (rex[2][2][j] + rex[2][3][j]);
            float r = 1.f/(1.f + __expf(-(ir + rt)));
            float z = 1.f/(1.f + __expf(-(izv + zt)));
            float x = inn + r*(nt + bh);
            float e2 = __expf(2.f*x);
            float n = 1.f - 2.f/(e2 + 1.f);          // tanh(x)
            float hn = (1.f - z)*n + z*hoj;
            hoj = dn ? 0.f : hn;                     // dn=false on last chunk step
            ((_Float16*)hbuf[cur^1])[j] = (_Float16)hoj;   // issue before y store
            y[((size_t)t*B_DIM + row)*H_DIM + j] = f2bf(hn);
        }
        __syncthreads();
        cur ^= 1;
    }

    if(g == 0) h_carry[(size_t)row*H_DIM + j] = hoj;  // raw carry
}

// ---------------------------------------------------------------------------
// Actor head stage 2: logits[rows,32] = ah[rows,:256 of ld] @ W_a2 + b_a2 - (1-avail)*1e10
// ---------------------------------------------------------------------------
__global__ __launch_bounds__(256)
void actor2_kernel(const u16* __restrict__ ah, int ld, const float* __restrict__ W_a2,
                   const float* __restrict__ b_a2, const float* __restrict__ avail,
                   float* __restrict__ logits)
{
    __shared__ u16 ahs[64][264];
    const int tid = threadIdx.x;
    const int r0 = blockIdx.x*64;
    {
        int row = tid & 63;
        int c0 = (tid >> 6) * 64;
        const uint4* gp = (const uint4*)(ah + (size_t)(r0+row)*ld + c0);
        #pragma unroll
        for(int q=0;q<8;q++){
            uint4 u = gp[q];
            u32* dst = (u32*)&ahs[row][c0 + q*8];
            dst[0]=u.x; dst[1]=u.y; dst[2]=u.z; dst[3]=u.w;
        }
    }
    __syncthreads();
    const int c  = tid & 31;
    const int rg = tid >> 5;   // 0..7
    float acc[8]={0.f,0.f,0.f,0.f,0.f,0.f,0.f,0.f};
    float bc = b_a2[c];
    for(int k=0;k<H_DIM;k+=4){
        float w0 = W_a2[(k+0)*A_DIM + c];
        float w1 = W_a2[(k+1)*A_DIM + c];
        float w2 = W_a2[(k+2)*A_DIM + c];
        float w3 = W_a2[(k+3)*A_DIM + c];
        #pragma unroll
        for(int rr=0;rr<8;rr++){
            uint2 av = *(const uint2*)&ahs[rg*8+rr][k];
            float2 p0 = bfpair(av.x), p1 = bfpair(av.y);
            acc[rr] = fmaf(p0.x,w0,fmaf(p0.y,w1,fmaf(p1.x,w2,fmaf(p1.y,w3,acc[rr]))));
        }
    }
    #pragma unroll
    for(int rr=0;rr<8;rr++){
        int grow = r0 + rg*8 + rr;
        float av = avail[(size_t)grow*A_DIM + c];
        logits[(size_t)grow*A_DIM + c] = acc[rr] + bc - (1.f-av)*1e10f;
    }
}

// ---------------------------------------------------------------------------
// Critic head stage 2: value[row] = ch[row,:256 of ld] @ W_c2 + b_c2. Wave per row.
// ---------------------------------------------------------------------------
__global__ __launch_bounds__(256)
void critic2_kernel(const u16* __restrict__ ch, int ld, const float* __restrict__ W_c2,
                    const float* __restrict__ b_c2, float* __restrict__ value)
{
    const int lane = threadIdx.x & 63;
    const int wid  = threadIdx.x >> 6;
    const int row  = blockIdx.x*4 + wid;
    uint2 av = *(const uint2*)(ch + (size_t)row*ld + lane*4);
    float2 p0 = bfpair(av.x), p1 = bfpair(av.y);
    float4 wv = *(const float4*)(W_c2 + lane*4);
    float acc = p0.x*wv.x + p0.y*wv.y + p1.x*wv.z + p1.y*wv.w;
    #pragma unroll
    for(int off=32; off>0; off>>=1) acc += __shfl_down(acc, off, 64);
    if(lane==0) value[row] = acc + b_c2[0];
}

// ---------------------------------------------------------------------------
extern "C" void kernel_launch(void* const* d_in, const int* in_sizes, int n_in,
                              void* d_out, int out_size, void* d_ws, size_t ws_size,
                              hipStream_t stream)
{
    const float* hidden = (const float*)d_in[0];
    const float* obs    = (const float*)d_in[1];
    const void*  dones  = d_in[2];
    const float* avail  = (const float*)d_in[3];
    const float* W_emb  = (const float*)d_in[4];
    const float* b_emb  = (const float*)d_in[5];
    const float* Wi     = (const float*)d_in[6];
    const float* bi     = (const float*)d_in[7];
    const float* Whr    = (const float*)d_in[8];
    const float* Whz    = (const float*)d_in[9];
    const float* Whn    = (const float*)d_in[10];
    const float* bhn    = (const float*)d_in[11];
    const float* W_a1   = (const float*)d_in[12];
    const float* b_a1   = (const float*)d_in[13];
    const float* W_a2   = (const float*)d_in[14];
    const float* b_a2   = (const float*)d_in[15];
    const float* W_c1   = (const float*)d_in[16];
    const float* b_c1   = (const float*)d_in[17];
    const float* W_c2   = (const float*)d_in[18];
    const float* b_c2   = (const float*)d_in[19];

    float* out_hidden = (float*)d_out;                       // 65536
    float* out_logits = out_hidden + (size_t)B_DIM*H_DIM;    // 4194304
    float* out_value  = out_logits + (size_t)TB*A_DIM;       // 131072

    // ---- workspace layout (chunk size adapted to ws_size, deterministic) ----
    const size_t fixed = 393216 + 393216 + 262144 + 65536 + 262144 + 256 + 2048;
    int Tc = 4;
    for(int cand = 512; cand >= 4; cand >>= 1){
        size_t need = fixed + (size_t)cand*(393216 /*gi*/ + 262144 /*emb|ac*/ + 131072 /*y*/);
        if(need <= ws_size){ Tc = cand; break; }
    }
    const int NC = T_DIM / Tc;

    uint8_t* ws = (uint8_t*)d_ws;
    size_t off = 0;
    u32*  wt_b    = (u32*)(ws + off); off += 393216;   // scan weights, packed f16
    u16*  wiT     = (u16*)(ws + off); off += 393216;   // Wi^T bf16 [768][256]
    u16*  wacT    = (u16*)(ws + off); off += 262144;   // [W_a1^T | W_c1^T] bf16 [512][256]
    u16*  wembT   = (u16*)(ws + off); off += 65536;    // W_emb^T bf16 [256][128]
    float* h_carry= (float*)(ws + off); off += 262144;
    int*  flags   = (int*)(ws + off); off += 256;
    float* b_ac   = (float*)(ws + off); off += 2048;   // b_a1|b_c1 (512 f32)
    u16*  gi_c    = (u16*)(ws + off); off += (size_t)Tc*393216;
    u16*  embac_c = (u16*)(ws + off); off += (size_t)Tc*262144;  // emb [Mc][256], later ac [Mc][512]
    u16*  y_c     = (u16*)(ws + off); off += (size_t)Tc*131072;
    u16*  emb_c   = embac_c;
    u16*  ac_c    = embac_c;

    zero_flags_kernel<<<1, 64, 0, stream>>>(flags);
    detect_kernel<<<64, 256, 0, stream>>>((const unsigned char*)dones, TB, flags);
    cvt_wt_kernel<<<384, 256, 0, stream>>>(Whr, Whz, Whn, wt_b);
    cvt_wT_kernel<<<768, 256, 0, stream>>>(Wi,   wiT,  256, 768);
    cvt_wT_kernel<<<256, 256, 0, stream>>>(W_a1, wacT,          256, 256);
    cvt_wT_kernel<<<256, 256, 0, stream>>>(W_c1, wacT + 65536,  256, 256);
    cvt_wT_kernel<<<128, 256, 0, stream>>>(W_emb, wembT, 128, 256);
    concat_bias_kernel<<<1, 256, 0, stream>>>(b_a1, b_c1, b_ac);
    hipMemcpyAsync(h_carry, hidden, (size_t)B_DIM*H_DIM*sizeof(float),
                   hipMemcpyDeviceToDevice, stream);

    const int Mc = Tc*B_DIM;
    const int gy = Mc/128;

    for(int c = 0; c < NC; ++c){
        const int t0 = c*Tc;
        const float* obs_c = obs + (size_t)t0*B_DIM*OBS_DIM;
        // emb = relu(obs @ W_emb + b_emb)  (MFMA, f32 A converted in staging)
        gemm_mfma_kernel<1,1><<<dim3(2,gy), 256, 0, stream>>>(obs_c, wembT, b_emb, emb_c, Mc, 256, 128);
        // gi = emb @ Wi + bi  (MFMA)
        gemm_mfma_kernel<0,0><<<dim3(6,gy), 256, 0, stream>>>(emb_c, wiT, bi, gi_c, Mc, 768, 256);
        // GRU scan chunk: 256 blocks (one per batch row) x 1024 threads
        scan_kernel<<<256, 1024, 0, stream>>>(gi_c, dones, flags, (const u32x4*)wt_b,
                                              bhn, h_carry, y_c, t0, Tc);
        // fused actor1|critic1 head: [Mc][512] = relu(y @ [W_a1|W_c1] + b_ac)
        gemm_mfma_kernel<1,0><<<dim3(4,gy), 256, 0, stream>>>(y_c, wacT, b_ac, ac_c, Mc, 512, 256);
        actor2_kernel<<<Mc/64, 256, 0, stream>>>(ac_c, 512, W_a2, b_a2,
                                                 avail + (size_t)t0*B_DIM*A_DIM,
                                                 out_logits + (size_t)t0*B_DIM*A_DIM);
        critic2_kernel<<<Mc/4, 256, 0, stream>>>(ac_c + 256, 512, W_c2, b_c2,
                                                 out_value + (size_t)t0*B_DIM);
    }

    hipMemcpyAsync(out_hidden, h_carry, (size_t)B_DIM*H_DIM*sizeof(float),
                   hipMemcpyDeviceToDevice, stream);
}